// Round 16
// baseline (2120.305 us; speedup 1.0000x reference)
//
#include <hip/hip_runtime.h>
#include <hip/hip_bf16.h>
#include <cstddef>

typedef _Float16 f16;
typedef f16 f16x8 __attribute__((ext_vector_type(8)));
typedef f16 f16x4 __attribute__((ext_vector_type(4)));
typedef f16 f16x16 __attribute__((ext_vector_type(16)));
typedef float f32x4 __attribute__((ext_vector_type(4)));

#define NNODES 10000
#define NEDGES 320000

// ---------------------------------------------------------------------------
// Batched weight packing: one launch packs all matrices.
// P[((ks*NB + nb)*64 + lane)*8 + i] = W[(nb*16+(lane&15))*ldw + k0 + ks*32 + 8*(lane>>4) + i]
// ---------------------------------------------------------------------------
struct PackJob { const float* W; f16* P; int Nout, K, ldw, k0; };
struct PackJobs { PackJob j[15]; };

__global__ void pack_all(PackJobs jobs) {
    const PackJob J = jobs.j[blockIdx.y];
    int idx = blockIdx.x * 256 + threadIdx.x;
    int total = J.Nout * J.K;
    if (idx >= total) return;
    int i = idx & 7;
    int l = (idx >> 3) & 63;
    int rest = idx >> 9;
    int NB = J.Nout >> 4;
    int nb = rest % NB;
    int ks = rest / NB;
    int k = ks * 32 + ((l >> 4) << 3) + i;
    int n = nb * 16 + (l & 15);
    J.P[idx] = (f16)J.W[(size_t)n * J.ldw + J.k0 + k];
}

// ---------------------------------------------------------------------------
// Generic C = A @ W^T + bias. AMODE: 0 = fp32 A (convert), 1 = f16 A.
// OMODE: 0 = f32 out, 1 = f16 out.
// ---------------------------------------------------------------------------
template <int AMODE, int OMODE>
__global__ void gemm_bias(const void* __restrict__ A_, const f16* __restrict__ P,
                          const float* __restrict__ bias, void* __restrict__ C_,
                          int M, int Nout, int K) {
    const int lane = threadIdx.x & 63, wave = threadIdx.x >> 6;
    const int wm = wave >> 1, wn = wave & 1;
    const int rb = blockIdx.x * 64 + wm * 32;
    const int cb = blockIdx.y * 64 + wn * 32;
    const int NB = Nout >> 4;
    const int kl = (lane >> 4) << 3;
    int r0 = rb + (lane & 15);
    int r1 = r0 + 16;
    int rc0 = r0 < M ? r0 : M - 1;
    int rc1 = r1 < M ? r1 : M - 1;
    f32x4 acc[2][2] = {};
    for (int ks = 0; ks < (K >> 5); ++ks) {
        int kb = ks * 32 + kl;
        f16x8 a0, a1;
        if constexpr (AMODE == 1) {
            const f16* A = (const f16*)A_;
            a0 = *(const f16x8*)(A + (size_t)rc0 * K + kb);
            a1 = *(const f16x8*)(A + (size_t)rc1 * K + kb);
        } else {
            const float* A = (const float*)A_;
            const float* p0 = A + (size_t)rc0 * K + kb;
            const float* p1 = A + (size_t)rc1 * K + kb;
#pragma unroll
            for (int i = 0; i < 8; ++i) { a0[i] = (f16)p0[i]; a1[i] = (f16)p1[i]; }
        }
#pragma unroll
        for (int nf = 0; nf < 2; ++nf) {
            int nb = (cb >> 4) + nf;
            f16x8 b = *(const f16x8*)(P + (((size_t)ks * NB + nb) * 64 + lane) * 8);
            acc[0][nf] = __builtin_amdgcn_mfma_f32_16x16x32_f16(a0, b, acc[0][nf], 0, 0, 0);
            acc[1][nf] = __builtin_amdgcn_mfma_f32_16x16x32_f16(a1, b, acc[1][nf], 0, 0, 0);
        }
    }
#pragma unroll
    for (int mf = 0; mf < 2; ++mf)
#pragma unroll
        for (int nf = 0; nf < 2; ++nf)
#pragma unroll
            for (int reg = 0; reg < 4; ++reg) {
                int row = rb + mf * 16 + ((lane >> 4) << 2) + reg;
                int col = cb + nf * 16 + (lane & 15);
                if (row < M) {
                    float v = acc[mf][nf][reg] + bias[col];
                    if constexpr (OMODE == 0)
                        ((float*)C_)[(size_t)row * Nout + col] = v;
                    else
                        ((f16*)C_)[(size_t)row * Nout + col] = (f16)v;
                }
            }
}

// ---------------------------------------------------------------------------
// Initial per-node message GEMMs (used once, after encode):
// Gs = unf16 @ Ws^T + bih, Gd = unf16 @ Wd^T, gate-interleaved layout
// G[node*1024 + (col&255)*4 + (col>>8)]. grid (157, 24): by<12 Gs, else Gd.
// ---------------------------------------------------------------------------
__global__ void gemm_gi2(const f16* __restrict__ A,
                         const f16* __restrict__ Ps, const f16* __restrict__ Pd,
                         const float* __restrict__ bias,
                         f16* __restrict__ Gs, f16* __restrict__ Gd, int M) {
    const int by = blockIdx.y;
    const bool isD = by >= 12;
    const f16* P = isD ? Pd : Ps;
    f16* G = isD ? Gd : Gs;
    const int byy = isD ? by - 12 : by;
    const int lane = threadIdx.x & 63, wave = threadIdx.x >> 6;
    const int wm = wave >> 1, wn = wave & 1;
    const int rb = blockIdx.x * 64 + wm * 32;
    const int cb = byy * 64 + wn * 32;
    const int NB = 48;
    const int kl = (lane >> 4) << 3;
    int r0 = rb + (lane & 15);
    int r1 = r0 + 16;
    int rc0 = r0 < M ? r0 : M - 1;
    int rc1 = r1 < M ? r1 : M - 1;
    f32x4 acc[2][2] = {};
    for (int ks = 0; ks < 8; ++ks) {
        int kb = ks * 32 + kl;
        f16x8 a0 = *(const f16x8*)(A + (size_t)rc0 * 256 + kb);
        f16x8 a1 = *(const f16x8*)(A + (size_t)rc1 * 256 + kb);
#pragma unroll
        for (int nf = 0; nf < 2; ++nf) {
            int nb = (cb >> 4) + nf;
            f16x8 b = *(const f16x8*)(P + (((size_t)ks * NB + nb) * 64 + lane) * 8);
            acc[0][nf] = __builtin_amdgcn_mfma_f32_16x16x32_f16(a0, b, acc[0][nf], 0, 0, 0);
            acc[1][nf] = __builtin_amdgcn_mfma_f32_16x16x32_f16(a1, b, acc[1][nf], 0, 0, 0);
        }
    }
#pragma unroll
    for (int mf = 0; mf < 2; ++mf)
#pragma unroll
        for (int nf = 0; nf < 2; ++nf)
#pragma unroll
            for (int reg = 0; reg < 4; ++reg) {
                int row = rb + mf * 16 + ((lane >> 4) << 2) + reg;
                int col = cb + nf * 16 + (lane & 15);
                if (row < M) {
                    float v = acc[mf][nf][reg];
                    if (!isD) v += bias[col];
                    G[(size_t)row * 1024 + (col & 255) * 4 + (col >> 8)] = (f16)v;
                }
            }
}

// fast activations; tail-safe without clamps (inf handled by rcp -> 0)
__device__ inline float sigmoidf_(float x) {
    return __fdividef(1.f, 1.f + __expf(-x));
}
__device__ inline float tanhf_(float x) {
    float t = __expf(2.f * x);
    return 1.f - __fdividef(2.f, t + 1.f);
}

// ---------------------------------------------------------------------------
// Fused edge GRU + segment-sum (dst-sorted order via eidx). Transposed MFMA
// (gh^T = Whh @ uef^T). In-place on uef; fused run-wise atomic segment-sum
// into agg (zeroed upstream). Packed f16 add for gs+gd.
// 1024 thr = 16 waves, acc[3][4] = 48 regs, LDS ~34 KB.
// ---------------------------------------------------------------------------
__global__ __launch_bounds__(1024, 4) void edge_gru(
        const f16* __restrict__ Gs, const f16* __restrict__ Gd,
        f16* __restrict__ uef,
        const int* __restrict__ src, const int* __restrict__ dst,
        const int* __restrict__ eidx,
        const f16* __restrict__ Phh, const float* __restrict__ bhh,
        float* __restrict__ agg) {
    __shared__ int s_eid[64];
    __shared__ int s_src[64];
    __shared__ int s_dst[64];
    __shared__ char lds_h[64 * 528];
    const int t = threadIdx.x;
    const int p0 = blockIdx.x * 64;
    if (t < 64) {
        int e = eidx[p0 + t];
        s_eid[t] = e;
        s_src[t] = src[e];
        s_dst[t] = dst[e];
    }
#pragma unroll
    for (int i = 0; i < 2; ++i) {
        int s = t + i * 1024;
        int row = s >> 5, seg = s & 31;
        int e = eidx[p0 + row];
        f16x8 v = *(const f16x8*)(uef + (size_t)e * 256 + seg * 8);
        *(f16x8*)(lds_h + row * 528 + seg * 16) = v;
    }
    __syncthreads();
    const int lane = t & 63;
    const int wv = t >> 6;
    const int klb = (lane >> 4) << 4;
    const int erow = lane & 15;
    f32x4 acc[3][4] = {};
#pragma unroll
    for (int ks = 0; ks < 8; ++ks) {
        f16x8 b[4];
#pragma unroll
        for (int eg = 0; eg < 4; ++eg)
            b[eg] = *(const f16x8*)(lds_h + (eg * 16 + erow) * 528 + ks * 64 + klb);
#pragma unroll
        for (int g = 0; g < 3; ++g) {
            f16x8 a = *(const f16x8*)(Phh + (size_t)g * 65536
                                      + (((size_t)ks * 16 + wv) * 64 + lane) * 8);
#pragma unroll
            for (int eg = 0; eg < 4; ++eg)
                acc[g][eg] = __builtin_amdgcn_mfma_f32_16x16x32_f16(a, b[eg], acc[g][eg], 0, 0, 0);
        }
    }
    __syncthreads();
    {
        const int j0 = wv * 16 + ((lane >> 4) << 2);
        const f32x4 bhr = *(const f32x4*)(bhh + j0);
        const f32x4 bhz = *(const f32x4*)(bhh + 256 + j0);
        const f32x4 bhn = *(const f32x4*)(bhh + 512 + j0);
#pragma unroll
        for (int eg = 0; eg < 4; ++eg) {
            const int rr = eg * 16 + erow;
            const int sn = s_src[rr], dn = s_dst[rr];
            f16x16 gsv = *(const f16x16*)(Gs + (size_t)sn * 1024 + j0 * 4);
            f16x16 gdv = *(const f16x16*)(Gd + (size_t)dn * 1024 + j0 * 4);
            f16x16 gsum = gsv + gdv;            // v_pk_add_f16
            f16x4 hv = *(const f16x4*)(lds_h + rr * 528 + j0 * 2);
            f16x4 outv;
#pragma unroll
            for (int q = 0; q < 4; ++q) {
                float ir = (float)gsum[q * 4 + 0];
                float iz = (float)gsum[q * 4 + 1];
                float in = (float)gsum[q * 4 + 2];
                float r = sigmoidf_(ir + acc[0][eg][q] + bhr[q]);
                float z = sigmoidf_(iz + acc[1][eg][q] + bhz[q]);
                float nn = tanhf_(in + r * (acc[2][eg][q] + bhn[q]));
                float h = (float)hv[q];
                outv[q] = (f16)(nn + z * (h - nn));
            }
            *(f16x4*)(lds_h + rr * 528 + j0 * 2) = outv;
        }
    }
    __syncthreads();
#pragma unroll
    for (int i = 0; i < 2; ++i) {
        int s = t + i * 1024;
        int row = s >> 5, seg = s & 31;
        f16x8 v = *(const f16x8*)(lds_h + row * 528 + seg * 16);
        *(f16x8*)(uef + (size_t)s_eid[row] * 256 + seg * 8) = v;
    }
    {
        const int c = t & 255;
        const int q = t >> 8;
        float a = 0.f;
        int d = s_dst[q * 16];
#pragma unroll
        for (int r = q * 16; r < q * 16 + 16; ++r) {
            a += (float)*(const f16*)(lds_h + r * 528 + c * 2);
            int dn = (r < 63) ? s_dst[r + 1] : -1;
            if (r == q * 16 + 15 || dn != d) {
                atomicAdd(&agg[(size_t)d * 256 + c], a);
                a = 0.f;
                d = dn;
            }
        }
    }
}

// ---------------------------------------------------------------------------
// Fused node GRU + next-iteration gi GEMMs. IN-PLACE on unf16.
// Block: 64 nodes x 256 cols, 1024 thr = 16 waves.
// Phase A: standard node GRU (agg, unf16 -> new unf16), new tile also kept
// in LDS. Also zeroes its agg rows (safe: after all phase-1 reads; next
// edge_gru is stream-ordered after this kernel).
// Phase B (doG): Gs/Gd = newU @ Ws/Wd^T for these 64 rows; 6 col-groups/wave.
// ---------------------------------------------------------------------------
__global__ __launch_bounds__(1024) void node_gru_gi(
        float* __restrict__ agg, f16* __restrict__ unf16,
        const f16* __restrict__ Pih, const f16* __restrict__ Phh,
        const float* __restrict__ bih, const float* __restrict__ bhh,
        const f16* __restrict__ Ps, const f16* __restrict__ Pd,
        const float* __restrict__ bie,
        f16* __restrict__ Gs, f16* __restrict__ Gd, int M, int doG) {
    __shared__ char lds_u[64 * 528];
    const int t = threadIdx.x;
    const int lane = t & 63, wave = t >> 6;
    const int wm = wave & 1, wn = wave >> 1;
    const int rb0 = blockIdx.x * 64;
    const int rb = rb0 + wm * 32;
    const int cb = wn * 32;
    const int nb0 = wn * 2;
    const int kl = (lane >> 4) << 3;
    int r0 = rb + (lane & 15), r1 = r0 + 16;
    int rc0 = r0 < M ? r0 : M - 1;
    int rc1 = r1 < M ? r1 : M - 1;
    f32x4 acc[4][2][2] = {};
#pragma unroll
    for (int ks = 0; ks < 8; ++ks) {
        const float* p0 = agg + (size_t)rc0 * 256 + ks * 32 + kl;
        const float* p1 = agg + (size_t)rc1 * 256 + ks * 32 + kl;
        f16x8 a0, a1;
#pragma unroll
        for (int i = 0; i < 8; ++i) { a0[i] = (f16)p0[i]; a1[i] = (f16)p1[i]; }
#pragma unroll
        for (int g = 0; g < 3; ++g) {
            const f16* Pg = Pih + (size_t)g * (256 * 256);
#pragma unroll
            for (int nf = 0; nf < 2; ++nf) {
                f16x8 b = *(const f16x8*)(Pg + (((size_t)ks * 16 + nb0 + nf) * 64 + lane) * 8);
                acc[g][0][nf] = __builtin_amdgcn_mfma_f32_16x16x32_f16(a0, b, acc[g][0][nf], 0, 0, 0);
                acc[g][1][nf] = __builtin_amdgcn_mfma_f32_16x16x32_f16(a1, b, acc[g][1][nf], 0, 0, 0);
            }
        }
    }
#pragma unroll
    for (int ks = 0; ks < 8; ++ks) {
        f16x8 a0 = *(const f16x8*)(unf16 + (size_t)rc0 * 256 + ks * 32 + kl);
        f16x8 a1 = *(const f16x8*)(unf16 + (size_t)rc1 * 256 + ks * 32 + kl);
#pragma unroll
        for (int g = 0; g < 3; ++g) {
            const f16* Pg = Phh + (size_t)g * (256 * 256);
            const int tgt = (g == 2) ? 3 : g;
#pragma unroll
            for (int nf = 0; nf < 2; ++nf) {
                f16x8 b = *(const f16x8*)(Pg + (((size_t)ks * 16 + nb0 + nf) * 64 + lane) * 8);
                acc[tgt][0][nf] = __builtin_amdgcn_mfma_f32_16x16x32_f16(a0, b, acc[tgt][0][nf], 0, 0, 0);
                acc[tgt][1][nf] = __builtin_amdgcn_mfma_f32_16x16x32_f16(a1, b, acc[tgt][1][nf], 0, 0, 0);
            }
        }
    }
    __syncthreads();   // all agg/unf reads done
    // zero this block's agg rows for the next iteration's edge atomics
    {
        int nrows = M - rb0;
        if (nrows > 64) nrows = 64;
        if (nrows > 0) {
            int totf = nrows * 256;
            for (int s = t * 4; s < totf; s += 4096)
                *(f32x4*)(agg + (size_t)rb0 * 256 + s) = f32x4{0.f, 0.f, 0.f, 0.f};
        }
    }
    // epilogue: write new unf to global (guarded) and to LDS (always)
#pragma unroll
    for (int mf = 0; mf < 2; ++mf) {
        const int lrow = wm * 32 + mf * 16 + ((lane >> 4) << 2);
#pragma unroll
        for (int nf = 0; nf < 2; ++nf) {
            const int j = cb + nf * 16 + (lane & 15);
            const float b_r = bih[j] + bhh[j];
            const float b_z = bih[256 + j] + bhh[256 + j];
            const float b_i = bih[512 + j];
            const float b_h = bhh[512 + j];
#pragma unroll
            for (int reg = 0; reg < 4; ++reg) {
                const int lr = lrow + reg;
                const int rr = rb0 + lr;
                float r = sigmoidf_(acc[0][mf][nf][reg] + b_r);
                float z = sigmoidf_(acc[1][mf][nf][reg] + b_z);
                float nn = tanhf_(acc[2][mf][nf][reg] + b_i + r * (acc[3][mf][nf][reg] + b_h));
                float h = (float)unf16[(size_t)(rr < M ? rr : M - 1) * 256 + j];
                f16 v = (f16)(nn + z * (h - nn));
                *(f16*)(lds_u + lr * 528 + j * 2) = v;
                if (rr < M) unf16[(size_t)rr * 256 + j] = v;
            }
        }
    }
    if (!doG) return;
    __syncthreads();
    // phase B: G = newU @ Ws/Wd^T, 6 sequential 16-col groups per wave
    const int wv = t >> 6;
    const int klb = (lane >> 4) << 4;
    const int arow = lane & 15;
#pragma unroll
    for (int cgi = 0; cgi < 6; ++cgi) {
        const int cg = wv * 6 + cgi;
        const bool isD = cg >= 48;
        const int nb = isD ? cg - 48 : cg;
        const f16* P = isD ? Pd : Ps;
        f16* G = isD ? Gd : Gs;
        f32x4 a4[4] = {};
#pragma unroll
        for (int ks = 0; ks < 8; ++ks) {
            f16x8 b = *(const f16x8*)(P + (((size_t)ks * 48 + nb) * 64 + lane) * 8);
#pragma unroll
            for (int mf = 0; mf < 4; ++mf) {
                f16x8 a = *(const f16x8*)(lds_u + (mf * 16 + arow) * 528 + ks * 64 + klb);
                a4[mf] = __builtin_amdgcn_mfma_f32_16x16x32_f16(a, b, a4[mf], 0, 0, 0);
            }
        }
        const int col = nb * 16 + (lane & 15);
        const float bv = isD ? 0.f : bie[col];
        const size_t goff = (size_t)(col & 255) * 4 + (col >> 8);
#pragma unroll
        for (int mf = 0; mf < 4; ++mf)
#pragma unroll
            for (int reg = 0; reg < 4; ++reg) {
                int grow = rb0 + mf * 16 + ((lane >> 4) << 2) + reg;
                if (grow < M)
                    G[(size_t)grow * 1024 + goff] = (f16)(a4[mf][reg] + bv);
            }
    }
}

// ---------------------------------------------------------------------------
// CSR build (dst-sorted edge order)
// ---------------------------------------------------------------------------
__global__ void hist_k(const int* __restrict__ dst, int* __restrict__ cnt, int E) {
    int e = blockIdx.x * 256 + threadIdx.x;
    if (e < E) atomicAdd(&cnt[dst[e]], 1);
}

__global__ void scan_k(const int* __restrict__ cnt, int* __restrict__ rowptr, int n) {
    __shared__ int s[1024];
    __shared__ int carry_s;
    if (threadIdx.x == 0) { carry_s = 0; rowptr[0] = 0; }
    __syncthreads();
    for (int base = 0; base < n; base += 1024) {
        int i = base + (int)threadIdx.x;
        int v = (i < n) ? cnt[i] : 0;
        s[threadIdx.x] = v;
        __syncthreads();
        for (int off = 1; off < 1024; off <<= 1) {
            int tv = (threadIdx.x >= (unsigned)off) ? s[threadIdx.x - off] : 0;
            __syncthreads();
            s[threadIdx.x] += tv;
            __syncthreads();
        }
        if (i < n) rowptr[i + 1] = carry_s + s[threadIdx.x];
        __syncthreads();
        if (threadIdx.x == 0) carry_s += s[1023];
        __syncthreads();
    }
}

__global__ void scatter_k(const int* __restrict__ dst, const int* __restrict__ rowptr,
                          int* __restrict__ cnt2, int* __restrict__ eidx, int E) {
    int e = blockIdx.x * 256 + threadIdx.x;
    if (e < E) {
        int d = dst[e];
        int p = rowptr[d] + atomicAdd(&cnt2[d], 1);
        eidx[p] = e;
    }
}

// ---------------------------------------------------------------------------
extern "C" void kernel_launch(void* const* d_in, const int* in_sizes, int n_in,
                              void* d_out, int out_size, void* d_ws, size_t ws_size,
                              hipStream_t stream) {
    (void)in_sizes; (void)n_in; (void)out_size; (void)ws_size;
    const float* nf    = (const float*)d_in[0];
    const float* ef    = (const float*)d_in[1];
    const int*   src   = (const int*)d_in[2];
    const int*   dst   = (const int*)d_in[3];
    const float* Wne   = (const float*)d_in[4];
    const float* bne   = (const float*)d_in[5];
    const float* Wee   = (const float*)d_in[6];
    const float* bee   = (const float*)d_in[7];
    const float* Wih_e = (const float*)d_in[8];
    const float* Whh_e = (const float*)d_in[9];
    const float* bih_e = (const float*)d_in[10];
    const float* bhh_e = (const float*)d_in[11];
    const float* Wih_n = (const float*)d_in[12];
    const float* Whh_n = (const float*)d_in[13];
    const float* bih_n = (const float*)d_in[14];
    const float* bhh_n = (const float*)d_in[15];
    const float* Wnd   = (const float*)d_in[16];
    const float* bnd   = (const float*)d_in[17];
    const float* Wed   = (const float*)d_in[18];
    const float* bed   = (const float*)d_in[19];

    char* ws = (char*)d_ws;
    size_t off = 0;
    auto alloc = [&](size_t bytes) -> void* {
        void* p = ws + off;
        off += (bytes + 255) & ~(size_t)255;
        return p;
    };
    f16*   uefA  = (f16*)alloc((size_t)NEDGES * 256 * 2);
    f16*   unf16 = (f16*)alloc((size_t)NNODES * 256 * 2);
    float* agg   = (float*)alloc((size_t)NNODES * 256 * 4);
    f16*   Gs    = (f16*)alloc((size_t)NNODES * 1024 * 2);
    f16*   Gd    = (f16*)alloc((size_t)NNODES * 1024 * 2);
    f16*   Ps_e  = (f16*)alloc((size_t)768 * 256 * 2);
    f16*   Pd_e  = (f16*)alloc((size_t)768 * 256 * 2);
    f16*   Phh_e = (f16*)alloc((size_t)3 * 256 * 256 * 2);
    f16*   Pih_n = (f16*)alloc((size_t)3 * 256 * 256 * 2);
    f16*   Phh_n = (f16*)alloc((size_t)3 * 256 * 256 * 2);
    f16*   Pne   = (f16*)alloc((size_t)256 * 128 * 2);
    f16*   Pee   = (f16*)alloc((size_t)256 * 64 * 2);
    f16*   Pnd   = (f16*)alloc((size_t)128 * 256 * 2);
    f16*   Ped   = (f16*)alloc((size_t)64 * 256 * 2);
    int* cnt    = (int*)alloc((size_t)NNODES * 4);
    int* cnt2   = (int*)alloc((size_t)NNODES * 4);
    int* rowptr = (int*)alloc((size_t)(NNODES + 1) * 4);
    int* eidx   = (int*)alloc((size_t)NEDGES * 4);

    hipMemsetAsync(cnt, 0, (size_t)NNODES * 4, stream);
    hipMemsetAsync(cnt2, 0, (size_t)NNODES * 4, stream);
    hipMemsetAsync(agg, 0, (size_t)NNODES * 256 * 4, stream);

    // pack all weights in one launch
    PackJobs jobs;
    jobs.j[0]  = {Wih_e, Ps_e, 768, 256, 512, 0};
    jobs.j[1]  = {Wih_e, Pd_e, 768, 256, 512, 256};
    for (int g = 0; g < 3; ++g) {
        jobs.j[2 + g] = {Whh_e + (size_t)g * 65536, Phh_e + (size_t)g * 65536, 256, 256, 256, 0};
        jobs.j[5 + g] = {Wih_n + (size_t)g * 65536, Pih_n + (size_t)g * 65536, 256, 256, 256, 0};
        jobs.j[8 + g] = {Whh_n + (size_t)g * 65536, Phh_n + (size_t)g * 65536, 256, 256, 256, 0};
    }
    jobs.j[11] = {Wne, Pne, 256, 128, 128, 0};
    jobs.j[12] = {Wee, Pee, 256, 64, 64, 0};
    jobs.j[13] = {Wnd, Pnd, 128, 256, 256, 0};
    jobs.j[14] = {Wed, Ped, 64, 256, 256, 0};
    pack_all<<<dim3(768, 15), 256, 0, stream>>>(jobs);

    // CSR by dst (gives dst-sorted eidx)
    hist_k<<<(NEDGES + 255) / 256, 256, 0, stream>>>(dst, cnt, NEDGES);
    scan_k<<<1, 1024, 0, stream>>>(cnt, rowptr, NNODES);
    scatter_k<<<(NEDGES + 255) / 256, 256, 0, stream>>>(dst, rowptr, cnt2, eidx, NEDGES);

    // encode
    gemm_bias<0, 1><<<dim3(157, 4), 256, 0, stream>>>(nf, Pne, bne, unf16, NNODES, 256, 128);
    gemm_bias<0, 1><<<dim3(5000, 4), 256, 0, stream>>>(ef, Pee, bee, uefA, NEDGES, 256, 64);

    // initial per-node messages
    gemm_gi2<<<dim3(157, 24), 256, 0, stream>>>(unf16, Ps_e, Pd_e, bih_e, Gs, Gd, NNODES);

    // message passing (gi for next iter fused into node_gru)
    for (int it = 0; it < 3; ++it) {
        edge_gru<<<5000, 1024, 0, stream>>>(Gs, Gd, uefA, src, dst, eidx, Phh_e, bhh_e, agg);
        node_gru_gi<<<157, 1024, 0, stream>>>(agg, unf16, Pih_n, Phh_n, bih_n, bhh_n,
                                              Ps_e, Pd_e, bih_e, Gs, Gd, NNODES,
                                              (it < 2) ? 1 : 0);
    }

    // decode
    gemm_bias<1, 0><<<dim3(157, 2), 256, 0, stream>>>(unf16, Pnd, bnd, d_out, NNODES, 128, 256);
    gemm_bias<1, 0><<<dim3(5000, 1), 256, 0, stream>>>(uefA, Ped, bed,
                                                       (float*)d_out + (size_t)NNODES * 128,
                                                       NEDGES, 64, 256);
}

// Round 18
// 1729.653 us; speedup vs baseline: 1.2259x; 1.2259x over previous
//
#include <hip/hip_runtime.h>
#include <hip/hip_bf16.h>
#include <cstddef>

typedef _Float16 f16;
typedef f16 f16x8 __attribute__((ext_vector_type(8)));
typedef f16 f16x4 __attribute__((ext_vector_type(4)));
typedef f16 f16x16 __attribute__((ext_vector_type(16)));
typedef float f32x4 __attribute__((ext_vector_type(4)));

#define NNODES 10000
#define NEDGES 320000

// ---------------------------------------------------------------------------
// Batched weight packing: one launch packs all matrices (proven in round 16).
// P[((ks*NB + nb)*64 + lane)*8 + i] = W[(nb*16+(lane&15))*ldw + k0 + ks*32 + 8*(lane>>4) + i]
// ---------------------------------------------------------------------------
struct PackJob { const float* W; f16* P; int Nout, K, ldw, k0; };
struct PackJobs { PackJob j[15]; };

__global__ void pack_all(PackJobs jobs) {
    const PackJob J = jobs.j[blockIdx.y];
    int idx = blockIdx.x * 256 + threadIdx.x;
    int total = J.Nout * J.K;
    if (idx >= total) return;
    int i = idx & 7;
    int l = (idx >> 3) & 63;
    int rest = idx >> 9;
    int NB = J.Nout >> 4;
    int nb = rest % NB;
    int ks = rest / NB;
    int k = ks * 32 + ((l >> 4) << 3) + i;
    int n = nb * 16 + (l & 15);
    J.P[idx] = (f16)J.W[(size_t)n * J.ldw + J.k0 + k];
}

// ---------------------------------------------------------------------------
// Generic C = A @ W^T + bias. AMODE: 0 = fp32 A (convert), 1 = f16 A.
// OMODE: 0 = f32 out, 1 = f16 out.
// ---------------------------------------------------------------------------
template <int AMODE, int OMODE>
__global__ void gemm_bias(const void* __restrict__ A_, const f16* __restrict__ P,
                          const float* __restrict__ bias, void* __restrict__ C_,
                          int M, int Nout, int K) {
    const int lane = threadIdx.x & 63, wave = threadIdx.x >> 6;
    const int wm = wave >> 1, wn = wave & 1;
    const int rb = blockIdx.x * 64 + wm * 32;
    const int cb = blockIdx.y * 64 + wn * 32;
    const int NB = Nout >> 4;
    const int kl = (lane >> 4) << 3;
    int r0 = rb + (lane & 15);
    int r1 = r0 + 16;
    int rc0 = r0 < M ? r0 : M - 1;
    int rc1 = r1 < M ? r1 : M - 1;
    f32x4 acc[2][2] = {};
    for (int ks = 0; ks < (K >> 5); ++ks) {
        int kb = ks * 32 + kl;
        f16x8 a0, a1;
        if constexpr (AMODE == 1) {
            const f16* A = (const f16*)A_;
            a0 = *(const f16x8*)(A + (size_t)rc0 * K + kb);
            a1 = *(const f16x8*)(A + (size_t)rc1 * K + kb);
        } else {
            const float* A = (const float*)A_;
            const float* p0 = A + (size_t)rc0 * K + kb;
            const float* p1 = A + (size_t)rc1 * K + kb;
#pragma unroll
            for (int i = 0; i < 8; ++i) { a0[i] = (f16)p0[i]; a1[i] = (f16)p1[i]; }
        }
#pragma unroll
        for (int nf = 0; nf < 2; ++nf) {
            int nb = (cb >> 4) + nf;
            f16x8 b = *(const f16x8*)(P + (((size_t)ks * NB + nb) * 64 + lane) * 8);
            acc[0][nf] = __builtin_amdgcn_mfma_f32_16x16x32_f16(a0, b, acc[0][nf], 0, 0, 0);
            acc[1][nf] = __builtin_amdgcn_mfma_f32_16x16x32_f16(a1, b, acc[1][nf], 0, 0, 0);
        }
    }
#pragma unroll
    for (int mf = 0; mf < 2; ++mf)
#pragma unroll
        for (int nf = 0; nf < 2; ++nf)
#pragma unroll
            for (int reg = 0; reg < 4; ++reg) {
                int row = rb + mf * 16 + ((lane >> 4) << 2) + reg;
                int col = cb + nf * 16 + (lane & 15);
                if (row < M) {
                    float v = acc[mf][nf][reg] + bias[col];
                    if constexpr (OMODE == 0)
                        ((float*)C_)[(size_t)row * Nout + col] = v;
                    else
                        ((f16*)C_)[(size_t)row * Nout + col] = (f16)v;
                }
            }
}

// ---------------------------------------------------------------------------
// Per-node message GEMMs: Gs = unf16 @ Ws^T + bih, Gd = unf16 @ Wd^T,
// gate-INTERLEAVED output G[node*1024 + (col&255)*4 + (col>>8)].
// grid (157, 24): by<12 -> Gs (with bias), by>=12 -> Gd.
// ---------------------------------------------------------------------------
__global__ void gemm_gi2(const f16* __restrict__ A,
                         const f16* __restrict__ Ps, const f16* __restrict__ Pd,
                         const float* __restrict__ bias,
                         f16* __restrict__ Gs, f16* __restrict__ Gd, int M) {
    const int by = blockIdx.y;
    const bool isD = by >= 12;
    const f16* P = isD ? Pd : Ps;
    f16* G = isD ? Gd : Gs;
    const int byy = isD ? by - 12 : by;
    const int lane = threadIdx.x & 63, wave = threadIdx.x >> 6;
    const int wm = wave >> 1, wn = wave & 1;
    const int rb = blockIdx.x * 64 + wm * 32;
    const int cb = byy * 64 + wn * 32;
    const int NB = 48;
    const int kl = (lane >> 4) << 3;
    int r0 = rb + (lane & 15);
    int r1 = r0 + 16;
    int rc0 = r0 < M ? r0 : M - 1;
    int rc1 = r1 < M ? r1 : M - 1;
    f32x4 acc[2][2] = {};
    for (int ks = 0; ks < 8; ++ks) {
        int kb = ks * 32 + kl;
        f16x8 a0 = *(const f16x8*)(A + (size_t)rc0 * 256 + kb);
        f16x8 a1 = *(const f16x8*)(A + (size_t)rc1 * 256 + kb);
#pragma unroll
        for (int nf = 0; nf < 2; ++nf) {
            int nb = (cb >> 4) + nf;
            f16x8 b = *(const f16x8*)(P + (((size_t)ks * NB + nb) * 64 + lane) * 8);
            acc[0][nf] = __builtin_amdgcn_mfma_f32_16x16x32_f16(a0, b, acc[0][nf], 0, 0, 0);
            acc[1][nf] = __builtin_amdgcn_mfma_f32_16x16x32_f16(a1, b, acc[1][nf], 0, 0, 0);
        }
    }
#pragma unroll
    for (int mf = 0; mf < 2; ++mf)
#pragma unroll
        for (int nf = 0; nf < 2; ++nf)
#pragma unroll
            for (int reg = 0; reg < 4; ++reg) {
                int row = rb + mf * 16 + ((lane >> 4) << 2) + reg;
                int col = cb + nf * 16 + (lane & 15);
                if (row < M) {
                    float v = acc[mf][nf][reg];
                    if (!isD) v += bias[col];
                    G[(size_t)row * 1024 + (col & 255) * 4 + (col >> 8)] = (f16)v;
                }
            }
}

// fast activations; tail-safe without clamps (inf handled by rcp -> 0)
__device__ inline float sigmoidf_(float x) {
    return __fdividef(1.f, 1.f + __expf(-x));
}
__device__ inline float tanhf_(float x) {
    float t = __expf(2.f * x);
    return 1.f - __fdividef(2.f, t + 1.f);
}

// ---------------------------------------------------------------------------
// Fused edge GRU + segment-sum (dst-sorted order via eidx, IDENTITY tile
// mapping — the XCD swizzle of round 17 correlated with replay divergence
// and is reverted). Transposed MFMA (gh^T = Whh @ uef^T). In-place on uef;
// fused run-wise atomic segment-sum into agg (zeroed upstream).
// 1024 thr = 16 waves, acc[3][4] = 48 regs, LDS ~34 KB.
// ---------------------------------------------------------------------------
__global__ __launch_bounds__(1024, 4) void edge_gru(
        const f16* __restrict__ Gs, const f16* __restrict__ Gd,
        f16* __restrict__ uef,
        const int* __restrict__ src, const int* __restrict__ dst,
        const int* __restrict__ eidx,
        const f16* __restrict__ Phh, const float* __restrict__ bhh,
        float* __restrict__ agg) {
    __shared__ int s_eid[64];
    __shared__ int s_src[64];
    __shared__ int s_dst[64];
    __shared__ char lds_h[64 * 528];
    const int t = threadIdx.x;
    const int p0 = blockIdx.x * 64;
    if (t < 64) {
        int e = eidx[p0 + t];
        s_eid[t] = e;
        s_src[t] = src[e];
        s_dst[t] = dst[e];
    }
#pragma unroll
    for (int i = 0; i < 2; ++i) {
        int s = t + i * 1024;
        int row = s >> 5, seg = s & 31;
        int e = eidx[p0 + row];
        f16x8 v = *(const f16x8*)(uef + (size_t)e * 256 + seg * 8);
        *(f16x8*)(lds_h + row * 528 + seg * 16) = v;
    }
    __syncthreads();
    const int lane = t & 63;
    const int wv = t >> 6;
    const int klb = (lane >> 4) << 4;
    const int erow = lane & 15;
    f32x4 acc[3][4] = {};
#pragma unroll
    for (int ks = 0; ks < 8; ++ks) {
        f16x8 b[4];
#pragma unroll
        for (int eg = 0; eg < 4; ++eg)
            b[eg] = *(const f16x8*)(lds_h + (eg * 16 + erow) * 528 + ks * 64 + klb);
#pragma unroll
        for (int g = 0; g < 3; ++g) {
            f16x8 a = *(const f16x8*)(Phh + (size_t)g * 65536
                                      + (((size_t)ks * 16 + wv) * 64 + lane) * 8);
#pragma unroll
            for (int eg = 0; eg < 4; ++eg)
                acc[g][eg] = __builtin_amdgcn_mfma_f32_16x16x32_f16(a, b[eg], acc[g][eg], 0, 0, 0);
        }
    }
    __syncthreads();
    {
        const int j0 = wv * 16 + ((lane >> 4) << 2);
        const f32x4 bhr = *(const f32x4*)(bhh + j0);
        const f32x4 bhz = *(const f32x4*)(bhh + 256 + j0);
        const f32x4 bhn = *(const f32x4*)(bhh + 512 + j0);
#pragma unroll
        for (int eg = 0; eg < 4; ++eg) {
            const int rr = eg * 16 + erow;
            const int sn = s_src[rr], dn = s_dst[rr];
            f16x16 gsv = *(const f16x16*)(Gs + (size_t)sn * 1024 + j0 * 4);
            f16x16 gdv = *(const f16x16*)(Gd + (size_t)dn * 1024 + j0 * 4);
            f16x4 hv = *(const f16x4*)(lds_h + rr * 528 + j0 * 2);
            f16x4 outv;
#pragma unroll
            for (int q = 0; q < 4; ++q) {
                float ir = (float)gsv[q * 4 + 0] + (float)gdv[q * 4 + 0];
                float iz = (float)gsv[q * 4 + 1] + (float)gdv[q * 4 + 1];
                float in = (float)gsv[q * 4 + 2] + (float)gdv[q * 4 + 2];
                float r = sigmoidf_(ir + acc[0][eg][q] + bhr[q]);
                float z = sigmoidf_(iz + acc[1][eg][q] + bhz[q]);
                float nn = tanhf_(in + r * (acc[2][eg][q] + bhn[q]));
                float h = (float)hv[q];
                outv[q] = (f16)(nn + z * (h - nn));
            }
            *(f16x4*)(lds_h + rr * 528 + j0 * 2) = outv;
        }
    }
    __syncthreads();
#pragma unroll
    for (int i = 0; i < 2; ++i) {
        int s = t + i * 1024;
        int row = s >> 5, seg = s & 31;
        f16x8 v = *(const f16x8*)(lds_h + row * 528 + seg * 16);
        *(f16x8*)(uef + (size_t)s_eid[row] * 256 + seg * 8) = v;
    }
    {
        const int c = t & 255;
        const int q = t >> 8;
        float a = 0.f;
        int d = s_dst[q * 16];
#pragma unroll
        for (int r = q * 16; r < q * 16 + 16; ++r) {
            a += (float)*(const f16*)(lds_h + r * 528 + c * 2);
            int dn = (r < 63) ? s_dst[r + 1] : -1;
            if (r == q * 16 + 15 || dn != d) {
                atomicAdd(&agg[(size_t)d * 256 + c], a);
                a = 0.f;
                d = dn;
            }
        }
    }
}

// ---------------------------------------------------------------------------
// Fused node GRU, IN-PLACE on unf16 (f16 state). Block: 64 nodes x 256 cols.
// ---------------------------------------------------------------------------
__global__ __launch_bounds__(1024) void node_gru(
        const float* __restrict__ agg, f16* __restrict__ unf16,
        const f16* __restrict__ Pih, const f16* __restrict__ Phh,
        const float* __restrict__ bih, const float* __restrict__ bhh, int M) {
    const int lane = threadIdx.x & 63, wave = threadIdx.x >> 6;
    const int wm = wave & 1, wn = wave >> 1;
    const int rb = blockIdx.x * 64 + wm * 32;
    const int cb = wn * 32;
    const int nb0 = wn * 2;
    const int kl = (lane >> 4) << 3;
    int r0 = rb + (lane & 15), r1 = r0 + 16;
    int rc0 = r0 < M ? r0 : M - 1;
    int rc1 = r1 < M ? r1 : M - 1;
    f32x4 acc[4][2][2] = {};
#pragma unroll
    for (int ks = 0; ks < 8; ++ks) {
        const float* p0 = agg + (size_t)rc0 * 256 + ks * 32 + kl;
        const float* p1 = agg + (size_t)rc1 * 256 + ks * 32 + kl;
        f16x8 a0, a1;
#pragma unroll
        for (int i = 0; i < 8; ++i) { a0[i] = (f16)p0[i]; a1[i] = (f16)p1[i]; }
#pragma unroll
        for (int g = 0; g < 3; ++g) {
            const f16* Pg = Pih + (size_t)g * (256 * 256);
#pragma unroll
            for (int nf = 0; nf < 2; ++nf) {
                f16x8 b = *(const f16x8*)(Pg + (((size_t)ks * 16 + nb0 + nf) * 64 + lane) * 8);
                acc[g][0][nf] = __builtin_amdgcn_mfma_f32_16x16x32_f16(a0, b, acc[g][0][nf], 0, 0, 0);
                acc[g][1][nf] = __builtin_amdgcn_mfma_f32_16x16x32_f16(a1, b, acc[g][1][nf], 0, 0, 0);
            }
        }
    }
#pragma unroll
    for (int ks = 0; ks < 8; ++ks) {
        f16x8 a0 = *(const f16x8*)(unf16 + (size_t)rc0 * 256 + ks * 32 + kl);
        f16x8 a1 = *(const f16x8*)(unf16 + (size_t)rc1 * 256 + ks * 32 + kl);
#pragma unroll
        for (int g = 0; g < 3; ++g) {
            const f16* Pg = Phh + (size_t)g * (256 * 256);
            const int tgt = (g == 2) ? 3 : g;
#pragma unroll
            for (int nf = 0; nf < 2; ++nf) {
                f16x8 b = *(const f16x8*)(Pg + (((size_t)ks * 16 + nb0 + nf) * 64 + lane) * 8);
                acc[tgt][0][nf] = __builtin_amdgcn_mfma_f32_16x16x32_f16(a0, b, acc[tgt][0][nf], 0, 0, 0);
                acc[tgt][1][nf] = __builtin_amdgcn_mfma_f32_16x16x32_f16(a1, b, acc[tgt][1][nf], 0, 0, 0);
            }
        }
    }
    __syncthreads();
#pragma unroll
    for (int mf = 0; mf < 2; ++mf) {
        const int row = rb + mf * 16 + ((lane >> 4) << 2);
#pragma unroll
        for (int nf = 0; nf < 2; ++nf) {
            const int j = cb + nf * 16 + (lane & 15);
            const float b_r = bih[j] + bhh[j];
            const float b_z = bih[256 + j] + bhh[256 + j];
            const float b_i = bih[512 + j];
            const float b_h = bhh[512 + j];
#pragma unroll
            for (int reg = 0; reg < 4; ++reg) {
                const int rr = row + reg;
                if (rr < M) {
                    float r = sigmoidf_(acc[0][mf][nf][reg] + b_r);
                    float z = sigmoidf_(acc[1][mf][nf][reg] + b_z);
                    float nn = tanhf_(acc[2][mf][nf][reg] + b_i + r * (acc[3][mf][nf][reg] + b_h));
                    float h = (float)unf16[(size_t)rr * 256 + j];
                    unf16[(size_t)rr * 256 + j] = (f16)(nn + z * (h - nn));
                }
            }
        }
    }
}

// ---------------------------------------------------------------------------
// CSR build (dst-sorted edge order)
// ---------------------------------------------------------------------------
__global__ void hist_k(const int* __restrict__ dst, int* __restrict__ cnt, int E) {
    int e = blockIdx.x * 256 + threadIdx.x;
    if (e < E) atomicAdd(&cnt[dst[e]], 1);
}

__global__ void scan_k(const int* __restrict__ cnt, int* __restrict__ rowptr, int n) {
    __shared__ int s[1024];
    __shared__ int carry_s;
    if (threadIdx.x == 0) { carry_s = 0; rowptr[0] = 0; }
    __syncthreads();
    for (int base = 0; base < n; base += 1024) {
        int i = base + (int)threadIdx.x;
        int v = (i < n) ? cnt[i] : 0;
        s[threadIdx.x] = v;
        __syncthreads();
        for (int off = 1; off < 1024; off <<= 1) {
            int tv = (threadIdx.x >= (unsigned)off) ? s[threadIdx.x - off] : 0;
            __syncthreads();
            s[threadIdx.x] += tv;
            __syncthreads();
        }
        if (i < n) rowptr[i + 1] = carry_s + s[threadIdx.x];
        __syncthreads();
        if (threadIdx.x == 0) carry_s += s[1023];
        __syncthreads();
    }
}

__global__ void scatter_k(const int* __restrict__ dst, const int* __restrict__ rowptr,
                          int* __restrict__ cnt2, int* __restrict__ eidx, int E) {
    int e = blockIdx.x * 256 + threadIdx.x;
    if (e < E) {
        int d = dst[e];
        int p = rowptr[d] + atomicAdd(&cnt2[d], 1);
        eidx[p] = e;
    }
}

// ---------------------------------------------------------------------------
extern "C" void kernel_launch(void* const* d_in, const int* in_sizes, int n_in,
                              void* d_out, int out_size, void* d_ws, size_t ws_size,
                              hipStream_t stream) {
    (void)in_sizes; (void)n_in; (void)out_size; (void)ws_size;
    const float* nf    = (const float*)d_in[0];
    const float* ef    = (const float*)d_in[1];
    const int*   src   = (const int*)d_in[2];
    const int*   dst   = (const int*)d_in[3];
    const float* Wne   = (const float*)d_in[4];
    const float* bne   = (const float*)d_in[5];
    const float* Wee   = (const float*)d_in[6];
    const float* bee   = (const float*)d_in[7];
    const float* Wih_e = (const float*)d_in[8];
    const float* Whh_e = (const float*)d_in[9];
    const float* bih_e = (const float*)d_in[10];
    const float* bhh_e = (const float*)d_in[11];
    const float* Wih_n = (const float*)d_in[12];
    const float* Whh_n = (const float*)d_in[13];
    const float* bih_n = (const float*)d_in[14];
    const float* bhh_n = (const float*)d_in[15];
    const float* Wnd   = (const float*)d_in[16];
    const float* bnd   = (const float*)d_in[17];
    const float* Wed   = (const float*)d_in[18];
    const float* bed   = (const float*)d_in[19];

    char* ws = (char*)d_ws;
    size_t off = 0;
    auto alloc = [&](size_t bytes) -> void* {
        void* p = ws + off;
        off += (bytes + 255) & ~(size_t)255;
        return p;
    };
    f16*   uefA  = (f16*)alloc((size_t)NEDGES * 256 * 2);
    f16*   unf16 = (f16*)alloc((size_t)NNODES * 256 * 2);
    float* agg   = (float*)alloc((size_t)NNODES * 256 * 4);
    f16*   Gs    = (f16*)alloc((size_t)NNODES * 1024 * 2);
    f16*   Gd    = (f16*)alloc((size_t)NNODES * 1024 * 2);
    f16*   Ps_e  = (f16*)alloc((size_t)768 * 256 * 2);
    f16*   Pd_e  = (f16*)alloc((size_t)768 * 256 * 2);
    f16*   Phh_e = (f16*)alloc((size_t)3 * 256 * 256 * 2);
    f16*   Pih_n = (f16*)alloc((size_t)3 * 256 * 256 * 2);
    f16*   Phh_n = (f16*)alloc((size_t)3 * 256 * 256 * 2);
    f16*   Pne   = (f16*)alloc((size_t)256 * 128 * 2);
    f16*   Pee   = (f16*)alloc((size_t)256 * 64 * 2);
    f16*   Pnd   = (f16*)alloc((size_t)128 * 256 * 2);
    f16*   Ped   = (f16*)alloc((size_t)64 * 256 * 2);
    int* cnt    = (int*)alloc((size_t)NNODES * 4);
    int* cnt2   = (int*)alloc((size_t)NNODES * 4);
    int* rowptr = (int*)alloc((size_t)(NNODES + 1) * 4);
    int* eidx   = (int*)alloc((size_t)NEDGES * 4);

    hipMemsetAsync(cnt, 0, (size_t)NNODES * 4, stream);
    hipMemsetAsync(cnt2, 0, (size_t)NNODES * 4, stream);

    // pack all weights in one launch
    PackJobs jobs;
    jobs.j[0]  = {Wih_e, Ps_e, 768, 256, 512, 0};
    jobs.j[1]  = {Wih_e, Pd_e, 768, 256, 512, 256};
    for (int g = 0; g < 3; ++g) {
        jobs.j[2 + g] = {Whh_e + (size_t)g * 65536, Phh_e + (size_t)g * 65536, 256, 256, 256, 0};
        jobs.j[5 + g] = {Wih_n + (size_t)g * 65536, Pih_n + (size_t)g * 65536, 256, 256, 256, 0};
        jobs.j[8 + g] = {Whh_n + (size_t)g * 65536, Phh_n + (size_t)g * 65536, 256, 256, 256, 0};
    }
    jobs.j[11] = {Wne, Pne, 256, 128, 128, 0};
    jobs.j[12] = {Wee, Pee, 256, 64, 64, 0};
    jobs.j[13] = {Wnd, Pnd, 128, 256, 256, 0};
    jobs.j[14] = {Wed, Ped, 64, 256, 256, 0};
    pack_all<<<dim3(768, 15), 256, 0, stream>>>(jobs);

    // CSR by dst (gives dst-sorted eidx)
    hist_k<<<(NEDGES + 255) / 256, 256, 0, stream>>>(dst, cnt, NEDGES);
    scan_k<<<1, 1024, 0, stream>>>(cnt, rowptr, NNODES);
    scatter_k<<<(NEDGES + 255) / 256, 256, 0, stream>>>(dst, rowptr, cnt2, eidx, NEDGES);

    // encode
    gemm_bias<0, 1><<<dim3(157, 4), 256, 0, stream>>>(nf, Pne, bne, unf16, NNODES, 256, 128);
    gemm_bias<0, 1><<<dim3(5000, 4), 256, 0, stream>>>(ef, Pee, bee, uefA, NEDGES, 256, 64);

    // message passing (round-15 structure, identity tile mapping)
    for (int it = 0; it < 3; ++it) {
        gemm_gi2<<<dim3(157, 24), 256, 0, stream>>>(unf16, Ps_e, Pd_e, bih_e, Gs, Gd, NNODES);
        hipMemsetAsync(agg, 0, (size_t)NNODES * 256 * 4, stream);
        edge_gru<<<5000, 1024, 0, stream>>>(Gs, Gd, uefA, src, dst, eidx, Phh_e, bhh_e, agg);
        node_gru<<<157, 1024, 0, stream>>>(agg, unf16, Pih_n, Phh_n, bih_n, bhh_n, NNODES);
    }

    // decode
    gemm_bias<1, 0><<<dim3(157, 2), 256, 0, stream>>>(unf16, Pnd, bnd, d_out, NNODES, 128, 256);
    gemm_bias<1, 0><<<dim3(5000, 1), 256, 0, stream>>>(uefA, Ped, bed,
                                                       (float*)d_out + (size_t)NNODES * 128,
                                                       NEDGES, 64, 256);
}

// Round 19
// 1590.279 us; speedup vs baseline: 1.3333x; 1.0876x over previous
//
#include <hip/hip_runtime.h>
#include <hip/hip_bf16.h>
#include <cstddef>

typedef _Float16 f16;
typedef f16 f16x8 __attribute__((ext_vector_type(8)));
typedef f16 f16x4 __attribute__((ext_vector_type(4)));
typedef f16 f16x16 __attribute__((ext_vector_type(16)));
typedef float f32x4 __attribute__((ext_vector_type(4)));

#define NNODES 10000
#define NEDGES 320000

// ---------------------------------------------------------------------------
// Batched weight packing: one launch packs all matrices.
// P[((ks*NB + nb)*64 + lane)*8 + i] = W[(nb*16+(lane&15))*ldw + k0 + ks*32 + 8*(lane>>4) + i]
// ---------------------------------------------------------------------------
struct PackJob { const float* W; f16* P; int Nout, K, ldw, k0; };
struct PackJobs { PackJob j[15]; };

__global__ void pack_all(PackJobs jobs) {
    const PackJob J = jobs.j[blockIdx.y];
    int idx = blockIdx.x * 256 + threadIdx.x;
    int total = J.Nout * J.K;
    if (idx >= total) return;
    int i = idx & 7;
    int l = (idx >> 3) & 63;
    int rest = idx >> 9;
    int NB = J.Nout >> 4;
    int nb = rest % NB;
    int ks = rest / NB;
    int k = ks * 32 + ((l >> 4) << 3) + i;
    int n = nb * 16 + (l & 15);
    J.P[idx] = (f16)J.W[(size_t)n * J.ldw + J.k0 + k];
}

// ---------------------------------------------------------------------------
// Generic C = A @ W^T + bias. AMODE: 0 = fp32 A (convert), 1 = f16 A.
// OMODE: 0 = f32 out, 1 = f16 out.
// ---------------------------------------------------------------------------
template <int AMODE, int OMODE>
__global__ void gemm_bias(const void* __restrict__ A_, const f16* __restrict__ P,
                          const float* __restrict__ bias, void* __restrict__ C_,
                          int M, int Nout, int K) {
    const int lane = threadIdx.x & 63, wave = threadIdx.x >> 6;
    const int wm = wave >> 1, wn = wave & 1;
    const int rb = blockIdx.x * 64 + wm * 32;
    const int cb = blockIdx.y * 64 + wn * 32;
    const int NB = Nout >> 4;
    const int kl = (lane >> 4) << 3;
    int r0 = rb + (lane & 15);
    int r1 = r0 + 16;
    int rc0 = r0 < M ? r0 : M - 1;
    int rc1 = r1 < M ? r1 : M - 1;
    f32x4 acc[2][2] = {};
    for (int ks = 0; ks < (K >> 5); ++ks) {
        int kb = ks * 32 + kl;
        f16x8 a0, a1;
        if constexpr (AMODE == 1) {
            const f16* A = (const f16*)A_;
            a0 = *(const f16x8*)(A + (size_t)rc0 * K + kb);
            a1 = *(const f16x8*)(A + (size_t)rc1 * K + kb);
        } else {
            const float* A = (const float*)A_;
            const float* p0 = A + (size_t)rc0 * K + kb;
            const float* p1 = A + (size_t)rc1 * K + kb;
#pragma unroll
            for (int i = 0; i < 8; ++i) { a0[i] = (f16)p0[i]; a1[i] = (f16)p1[i]; }
        }
#pragma unroll
        for (int nf = 0; nf < 2; ++nf) {
            int nb = (cb >> 4) + nf;
            f16x8 b = *(const f16x8*)(P + (((size_t)ks * NB + nb) * 64 + lane) * 8);
            acc[0][nf] = __builtin_amdgcn_mfma_f32_16x16x32_f16(a0, b, acc[0][nf], 0, 0, 0);
            acc[1][nf] = __builtin_amdgcn_mfma_f32_16x16x32_f16(a1, b, acc[1][nf], 0, 0, 0);
        }
    }
#pragma unroll
    for (int mf = 0; mf < 2; ++mf)
#pragma unroll
        for (int nf = 0; nf < 2; ++nf)
#pragma unroll
            for (int reg = 0; reg < 4; ++reg) {
                int row = rb + mf * 16 + ((lane >> 4) << 2) + reg;
                int col = cb + nf * 16 + (lane & 15);
                if (row < M) {
                    float v = acc[mf][nf][reg] + bias[col];
                    if constexpr (OMODE == 0)
                        ((float*)C_)[(size_t)row * Nout + col] = v;
                    else
                        ((f16*)C_)[(size_t)row * Nout + col] = (f16)v;
                }
            }
}

// ---------------------------------------------------------------------------
// Per-node message GEMMs: Gs = unf16 @ Ws^T + bih, Gd = unf16 @ Wd^T,
// gate-INTERLEAVED output G[node*1024 + (col&255)*4 + (col>>8)].
// grid (157, 24): by<12 -> Gs (with bias), by>=12 -> Gd.
// ---------------------------------------------------------------------------
__global__ void gemm_gi2(const f16* __restrict__ A,
                         const f16* __restrict__ Ps, const f16* __restrict__ Pd,
                         const float* __restrict__ bias,
                         f16* __restrict__ Gs, f16* __restrict__ Gd, int M) {
    const int by = blockIdx.y;
    const bool isD = by >= 12;
    const f16* P = isD ? Pd : Ps;
    f16* G = isD ? Gd : Gs;
    const int byy = isD ? by - 12 : by;
    const int lane = threadIdx.x & 63, wave = threadIdx.x >> 6;
    const int wm = wave >> 1, wn = wave & 1;
    const int rb = blockIdx.x * 64 + wm * 32;
    const int cb = byy * 64 + wn * 32;
    const int NB = 48;
    const int kl = (lane >> 4) << 3;
    int r0 = rb + (lane & 15);
    int r1 = r0 + 16;
    int rc0 = r0 < M ? r0 : M - 1;
    int rc1 = r1 < M ? r1 : M - 1;
    f32x4 acc[2][2] = {};
    for (int ks = 0; ks < 8; ++ks) {
        int kb = ks * 32 + kl;
        f16x8 a0 = *(const f16x8*)(A + (size_t)rc0 * 256 + kb);
        f16x8 a1 = *(const f16x8*)(A + (size_t)rc1 * 256 + kb);
#pragma unroll
        for (int nf = 0; nf < 2; ++nf) {
            int nb = (cb >> 4) + nf;
            f16x8 b = *(const f16x8*)(P + (((size_t)ks * NB + nb) * 64 + lane) * 8);
            acc[0][nf] = __builtin_amdgcn_mfma_f32_16x16x32_f16(a0, b, acc[0][nf], 0, 0, 0);
            acc[1][nf] = __builtin_amdgcn_mfma_f32_16x16x32_f16(a1, b, acc[1][nf], 0, 0, 0);
        }
    }
#pragma unroll
    for (int mf = 0; mf < 2; ++mf)
#pragma unroll
        for (int nf = 0; nf < 2; ++nf)
#pragma unroll
            for (int reg = 0; reg < 4; ++reg) {
                int row = rb + mf * 16 + ((lane >> 4) << 2) + reg;
                int col = cb + nf * 16 + (lane & 15);
                if (row < M) {
                    float v = acc[mf][nf][reg];
                    if (!isD) v += bias[col];
                    G[(size_t)row * 1024 + (col & 255) * 4 + (col >> 8)] = (f16)v;
                }
            }
}

// fast activations; tail-safe without clamps (inf handled by rcp -> 0)
__device__ inline float sigmoidf_(float x) {
    return __fdividef(1.f, 1.f + __expf(-x));
}
__device__ inline float tanhf_(float x) {
    float t = __expf(2.f * x);
    return 1.f - __fdividef(2.f, t + 1.f);
}

// ---------------------------------------------------------------------------
// Fused edge GRU + segment-sum v12: 32-edge tiles, 512 thr = 8 waves,
// grid 10000 (identity mapping). Wave tile = 32 edges x 32 cols
// (acc[3][2][2] = 48 regs, ~112 total -> 4 waves/SIMD) so TWO independent
// 8-wave blocks co-reside per CU and their phases overlap (vs one 16-wave
// block before). Transposed MFMA (gh^T = Whh @ uef^T), in-place on uef,
// fused run-wise atomic segment-sum into agg (zeroed upstream).
// LDS ~17 KB.
// ---------------------------------------------------------------------------
__global__ __launch_bounds__(512, 4) void edge_gru(
        const f16* __restrict__ Gs, const f16* __restrict__ Gd,
        f16* __restrict__ uef,
        const int* __restrict__ src, const int* __restrict__ dst,
        const int* __restrict__ eidx,
        const f16* __restrict__ Phh, const float* __restrict__ bhh,
        float* __restrict__ agg) {
    __shared__ int s_eid[32];
    __shared__ int s_src[32];
    __shared__ int s_dst[32];
    __shared__ char lds_h[32 * 528];
    const int t = threadIdx.x;
    const int p0 = blockIdx.x * 32;
    if (t < 32) {
        int e = eidx[p0 + t];
        s_eid[t] = e;
        s_src[t] = src[e];
        s_dst[t] = dst[e];
    }
    // stage uef rows: 32 rows x 32 segs(16B) = 1024 segs / 512 thr = 2 iters
#pragma unroll
    for (int i = 0; i < 2; ++i) {
        int s = t + i * 512;
        int row = s >> 5, seg = s & 31;
        int e = eidx[p0 + row];
        f16x8 v = *(const f16x8*)(uef + (size_t)e * 256 + seg * 8);
        *(f16x8*)(lds_h + row * 528 + seg * 16) = v;
    }
    __syncthreads();
    const int lane = t & 63;
    const int wv = t >> 6;               // 8 waves, 32 cols each
    const int klb = (lane >> 4) << 4;
    const int erow = lane & 15;
    f32x4 acc[3][2][2] = {};             // [gate][jg][eg]
    // gh^T = Whh @ uef^T  (K = 256)
#pragma unroll
    for (int ks = 0; ks < 8; ++ks) {
        f16x8 b[2];
#pragma unroll
        for (int eg = 0; eg < 2; ++eg)
            b[eg] = *(const f16x8*)(lds_h + (eg * 16 + erow) * 528 + ks * 64 + klb);
#pragma unroll
        for (int g = 0; g < 3; ++g) {
#pragma unroll
            for (int jg = 0; jg < 2; ++jg) {
                f16x8 a = *(const f16x8*)(Phh + (size_t)g * 65536
                                          + (((size_t)ks * 16 + wv * 2 + jg) * 64 + lane) * 8);
#pragma unroll
                for (int eg = 0; eg < 2; ++eg)
                    acc[g][jg][eg] = __builtin_amdgcn_mfma_f32_16x16x32_f16(a, b[eg], acc[g][jg][eg], 0, 0, 0);
            }
        }
    }
    __syncthreads();   // all MFMA reads done before in-place lds_h rewrite
    // epilogue: j quad = (wv*2+jg)*16 + (lane>>4)*4, edge = eg*16 + erow
#pragma unroll
    for (int jg = 0; jg < 2; ++jg) {
        const int j0 = (wv * 2 + jg) * 16 + ((lane >> 4) << 2);
        const f32x4 bhr = *(const f32x4*)(bhh + j0);
        const f32x4 bhz = *(const f32x4*)(bhh + 256 + j0);
        const f32x4 bhn = *(const f32x4*)(bhh + 512 + j0);
#pragma unroll
        for (int eg = 0; eg < 2; ++eg) {
            const int rr = eg * 16 + erow;
            const int sn = s_src[rr], dn = s_dst[rr];
            f16x16 gsv = *(const f16x16*)(Gs + (size_t)sn * 1024 + j0 * 4);
            f16x16 gdv = *(const f16x16*)(Gd + (size_t)dn * 1024 + j0 * 4);
            f16x4 hv = *(const f16x4*)(lds_h + rr * 528 + j0 * 2);
            f16x4 outv;
#pragma unroll
            for (int q = 0; q < 4; ++q) {
                float ir = (float)gsv[q * 4 + 0] + (float)gdv[q * 4 + 0];
                float iz = (float)gsv[q * 4 + 1] + (float)gdv[q * 4 + 1];
                float in = (float)gsv[q * 4 + 2] + (float)gdv[q * 4 + 2];
                float r = sigmoidf_(ir + acc[0][jg][eg][q] + bhr[q]);
                float z = sigmoidf_(iz + acc[1][jg][eg][q] + bhz[q]);
                float nn = tanhf_(in + r * (acc[2][jg][eg][q] + bhn[q]));
                float h = (float)hv[q];
                outv[q] = (f16)(nn + z * (h - nn));
            }
            *(f16x4*)(lds_h + rr * 528 + j0 * 2) = outv;
        }
    }
    __syncthreads();
    // coalesced-per-row copy-out (scatter to original edge ids)
#pragma unroll
    for (int i = 0; i < 2; ++i) {
        int s = t + i * 512;
        int row = s >> 5, seg = s & 31;
        f16x8 v = *(const f16x8*)(lds_h + row * 528 + seg * 16);
        *(f16x8*)(uef + (size_t)s_eid[row] * 256 + seg * 8) = v;
    }
    // fused segment-sum: thread owns col c, half q (rows q*16 .. q*16+15)
    {
        const int c = t & 255;
        const int q = t >> 8;            // 0..1
        float a = 0.f;
        int d = s_dst[q * 16];
#pragma unroll
        for (int r = q * 16; r < q * 16 + 16; ++r) {
            a += (float)*(const f16*)(lds_h + r * 528 + c * 2);
            int dn = (r < 31) ? s_dst[r + 1] : -1;
            if (r == q * 16 + 15 || dn != d) {
                atomicAdd(&agg[(size_t)d * 256 + c], a);
                a = 0.f;
                d = dn;
            }
        }
    }
}

// ---------------------------------------------------------------------------
// Fused node GRU, IN-PLACE on unf16 (f16 state). Block: 64 nodes x 256 cols.
// ---------------------------------------------------------------------------
__global__ __launch_bounds__(1024) void node_gru(
        const float* __restrict__ agg, f16* __restrict__ unf16,
        const f16* __restrict__ Pih, const f16* __restrict__ Phh,
        const float* __restrict__ bih, const float* __restrict__ bhh, int M) {
    const int lane = threadIdx.x & 63, wave = threadIdx.x >> 6;
    const int wm = wave & 1, wn = wave >> 1;
    const int rb = blockIdx.x * 64 + wm * 32;
    const int cb = wn * 32;
    const int nb0 = wn * 2;
    const int kl = (lane >> 4) << 3;
    int r0 = rb + (lane & 15), r1 = r0 + 16;
    int rc0 = r0 < M ? r0 : M - 1;
    int rc1 = r1 < M ? r1 : M - 1;
    f32x4 acc[4][2][2] = {};
#pragma unroll
    for (int ks = 0; ks < 8; ++ks) {
        const float* p0 = agg + (size_t)rc0 * 256 + ks * 32 + kl;
        const float* p1 = agg + (size_t)rc1 * 256 + ks * 32 + kl;
        f16x8 a0, a1;
#pragma unroll
        for (int i = 0; i < 8; ++i) { a0[i] = (f16)p0[i]; a1[i] = (f16)p1[i]; }
#pragma unroll
        for (int g = 0; g < 3; ++g) {
            const f16* Pg = Pih + (size_t)g * (256 * 256);
#pragma unroll
            for (int nf = 0; nf < 2; ++nf) {
                f16x8 b = *(const f16x8*)(Pg + (((size_t)ks * 16 + nb0 + nf) * 64 + lane) * 8);
                acc[g][0][nf] = __builtin_amdgcn_mfma_f32_16x16x32_f16(a0, b, acc[g][0][nf], 0, 0, 0);
                acc[g][1][nf] = __builtin_amdgcn_mfma_f32_16x16x32_f16(a1, b, acc[g][1][nf], 0, 0, 0);
            }
        }
    }
#pragma unroll
    for (int ks = 0; ks < 8; ++ks) {
        f16x8 a0 = *(const f16x8*)(unf16 + (size_t)rc0 * 256 + ks * 32 + kl);
        f16x8 a1 = *(const f16x8*)(unf16 + (size_t)rc1 * 256 + ks * 32 + kl);
#pragma unroll
        for (int g = 0; g < 3; ++g) {
            const f16* Pg = Phh + (size_t)g * (256 * 256);
            const int tgt = (g == 2) ? 3 : g;
#pragma unroll
            for (int nf = 0; nf < 2; ++nf) {
                f16x8 b = *(const f16x8*)(Pg + (((size_t)ks * 16 + nb0 + nf) * 64 + lane) * 8);
                acc[tgt][0][nf] = __builtin_amdgcn_mfma_f32_16x16x32_f16(a0, b, acc[tgt][0][nf], 0, 0, 0);
                acc[tgt][1][nf] = __builtin_amdgcn_mfma_f32_16x16x32_f16(a1, b, acc[tgt][1][nf], 0, 0, 0);
            }
        }
    }
    __syncthreads();
#pragma unroll
    for (int mf = 0; mf < 2; ++mf) {
        const int row = rb + mf * 16 + ((lane >> 4) << 2);
#pragma unroll
        for (int nf = 0; nf < 2; ++nf) {
            const int j = cb + nf * 16 + (lane & 15);
            const float b_r = bih[j] + bhh[j];
            const float b_z = bih[256 + j] + bhh[256 + j];
            const float b_i = bih[512 + j];
            const float b_h = bhh[512 + j];
#pragma unroll
            for (int reg = 0; reg < 4; ++reg) {
                const int rr = row + reg;
                if (rr < M) {
                    float r = sigmoidf_(acc[0][mf][nf][reg] + b_r);
                    float z = sigmoidf_(acc[1][mf][nf][reg] + b_z);
                    float nn = tanhf_(acc[2][mf][nf][reg] + b_i + r * (acc[3][mf][nf][reg] + b_h));
                    float h = (float)unf16[(size_t)rr * 256 + j];
                    unf16[(size_t)rr * 256 + j] = (f16)(nn + z * (h - nn));
                }
            }
        }
    }
}

// ---------------------------------------------------------------------------
// CSR build (dst-sorted edge order)
// ---------------------------------------------------------------------------
__global__ void hist_k(const int* __restrict__ dst, int* __restrict__ cnt, int E) {
    int e = blockIdx.x * 256 + threadIdx.x;
    if (e < E) atomicAdd(&cnt[dst[e]], 1);
}

__global__ void scan_k(const int* __restrict__ cnt, int* __restrict__ rowptr, int n) {
    __shared__ int s[1024];
    __shared__ int carry_s;
    if (threadIdx.x == 0) { carry_s = 0; rowptr[0] = 0; }
    __syncthreads();
    for (int base = 0; base < n; base += 1024) {
        int i = base + (int)threadIdx.x;
        int v = (i < n) ? cnt[i] : 0;
        s[threadIdx.x] = v;
        __syncthreads();
        for (int off = 1; off < 1024; off <<= 1) {
            int tv = (threadIdx.x >= (unsigned)off) ? s[threadIdx.x - off] : 0;
            __syncthreads();
            s[threadIdx.x] += tv;
            __syncthreads();
        }
        if (i < n) rowptr[i + 1] = carry_s + s[threadIdx.x];
        __syncthreads();
        if (threadIdx.x == 0) carry_s += s[1023];
        __syncthreads();
    }
}

__global__ void scatter_k(const int* __restrict__ dst, const int* __restrict__ rowptr,
                          int* __restrict__ cnt2, int* __restrict__ eidx, int E) {
    int e = blockIdx.x * 256 + threadIdx.x;
    if (e < E) {
        int d = dst[e];
        int p = rowptr[d] + atomicAdd(&cnt2[d], 1);
        eidx[p] = e;
    }
}

// ---------------------------------------------------------------------------
extern "C" void kernel_launch(void* const* d_in, const int* in_sizes, int n_in,
                              void* d_out, int out_size, void* d_ws, size_t ws_size,
                              hipStream_t stream) {
    (void)in_sizes; (void)n_in; (void)out_size; (void)ws_size;
    const float* nf    = (const float*)d_in[0];
    const float* ef    = (const float*)d_in[1];
    const int*   src   = (const int*)d_in[2];
    const int*   dst   = (const int*)d_in[3];
    const float* Wne   = (const float*)d_in[4];
    const float* bne   = (const float*)d_in[5];
    const float* Wee   = (const float*)d_in[6];
    const float* bee   = (const float*)d_in[7];
    const float* Wih_e = (const float*)d_in[8];
    const float* Whh_e = (const float*)d_in[9];
    const float* bih_e = (const float*)d_in[10];
    const float* bhh_e = (const float*)d_in[11];
    const float* Wih_n = (const float*)d_in[12];
    const float* Whh_n = (const float*)d_in[13];
    const float* bih_n = (const float*)d_in[14];
    const float* bhh_n = (const float*)d_in[15];
    const float* Wnd   = (const float*)d_in[16];
    const float* bnd   = (const float*)d_in[17];
    const float* Wed   = (const float*)d_in[18];
    const float* bed   = (const float*)d_in[19];

    char* ws = (char*)d_ws;
    size_t off = 0;
    auto alloc = [&](size_t bytes) -> void* {
        void* p = ws + off;
        off += (bytes + 255) & ~(size_t)255;
        return p;
    };
    f16*   uefA  = (f16*)alloc((size_t)NEDGES * 256 * 2);
    f16*   unf16 = (f16*)alloc((size_t)NNODES * 256 * 2);
    float* agg   = (float*)alloc((size_t)NNODES * 256 * 4);
    f16*   Gs    = (f16*)alloc((size_t)NNODES * 1024 * 2);
    f16*   Gd    = (f16*)alloc((size_t)NNODES * 1024 * 2);
    f16*   Ps_e  = (f16*)alloc((size_t)768 * 256 * 2);
    f16*   Pd_e  = (f16*)alloc((size_t)768 * 256 * 2);
    f16*   Phh_e = (f16*)alloc((size_t)3 * 256 * 256 * 2);
    f16*   Pih_n = (f16*)alloc((size_t)3 * 256 * 256 * 2);
    f16*   Phh_n = (f16*)alloc((size_t)3 * 256 * 256 * 2);
    f16*   Pne   = (f16*)alloc((size_t)256 * 128 * 2);
    f16*   Pee   = (f16*)alloc((size_t)256 * 64 * 2);
    f16*   Pnd   = (f16*)alloc((size_t)128 * 256 * 2);
    f16*   Ped   = (f16*)alloc((size_t)64 * 256 * 2);
    int* cnt    = (int*)alloc((size_t)NNODES * 4);
    int* cnt2   = (int*)alloc((size_t)NNODES * 4);
    int* rowptr = (int*)alloc((size_t)(NNODES + 1) * 4);
    int* eidx   = (int*)alloc((size_t)NEDGES * 4);

    hipMemsetAsync(cnt, 0, (size_t)NNODES * 4, stream);
    hipMemsetAsync(cnt2, 0, (size_t)NNODES * 4, stream);

    // pack all weights in one launch
    PackJobs jobs;
    jobs.j[0]  = {Wih_e, Ps_e, 768, 256, 512, 0};
    jobs.j[1]  = {Wih_e, Pd_e, 768, 256, 512, 256};
    for (int g = 0; g < 3; ++g) {
        jobs.j[2 + g] = {Whh_e + (size_t)g * 65536, Phh_e + (size_t)g * 65536, 256, 256, 256, 0};
        jobs.j[5 + g] = {Wih_n + (size_t)g * 65536, Pih_n + (size_t)g * 65536, 256, 256, 256, 0};
        jobs.j[8 + g] = {Whh_n + (size_t)g * 65536, Phh_n + (size_t)g * 65536, 256, 256, 256, 0};
    }
    jobs.j[11] = {Wne, Pne, 256, 128, 128, 0};
    jobs.j[12] = {Wee, Pee, 256, 64, 64, 0};
    jobs.j[13] = {Wnd, Pnd, 128, 256, 256, 0};
    jobs.j[14] = {Wed, Ped, 64, 256, 256, 0};
    pack_all<<<dim3(768, 15), 256, 0, stream>>>(jobs);

    // CSR by dst (gives dst-sorted eidx)
    hist_k<<<(NEDGES + 255) / 256, 256, 0, stream>>>(dst, cnt, NEDGES);
    scan_k<<<1, 1024, 0, stream>>>(cnt, rowptr, NNODES);
    scatter_k<<<(NEDGES + 255) / 256, 256, 0, stream>>>(dst, rowptr, cnt2, eidx, NEDGES);

    // encode
    gemm_bias<0, 1><<<dim3(157, 4), 256, 0, stream>>>(nf, Pne, bne, unf16, NNODES, 256, 128);
    gemm_bias<0, 1><<<dim3(5000, 4), 256, 0, stream>>>(ef, Pee, bee, uefA, NEDGES, 256, 64);

    // message passing
    for (int it = 0; it < 3; ++it) {
        gemm_gi2<<<dim3(157, 24), 256, 0, stream>>>(unf16, Ps_e, Pd_e, bih_e, Gs, Gd, NNODES);
        hipMemsetAsync(agg, 0, (size_t)NNODES * 256 * 4, stream);
        edge_gru<<<10000, 512, 0, stream>>>(Gs, Gd, uefA, src, dst, eidx, Phh_e, bhh_e, agg);
        node_gru<<<157, 1024, 0, stream>>>(agg, unf16, Pih_n, Phh_n, bih_n, bhh_n, NNODES);
    }

    // decode
    gemm_bias<1, 0><<<dim3(157, 2), 256, 0, stream>>>(unf16, Pnd, bnd, d_out, NNODES, 128, 256);
    gemm_bias<1, 0><<<dim3(5000, 1), 256, 0, stream>>>(uefA, Ped, bed,
                                                       (float*)d_out + (size_t)NNODES * 128,
                                                       NEDGES, 64, 256);
}

// Round 20
// 1588.292 us; speedup vs baseline: 1.3350x; 1.0013x over previous
//
#include <hip/hip_runtime.h>
#include <hip/hip_bf16.h>
#include <cstddef>

typedef _Float16 f16;
typedef f16 f16x8 __attribute__((ext_vector_type(8)));
typedef f16 f16x4 __attribute__((ext_vector_type(4)));
typedef f16 f16x16 __attribute__((ext_vector_type(16)));
typedef float f32x4 __attribute__((ext_vector_type(4)));

#define NNODES 10000
#define NEDGES 320000

// ---------------------------------------------------------------------------
// Batched weight packing: one launch packs all matrices.
// ---------------------------------------------------------------------------
struct PackJob { const float* W; f16* P; int Nout, K, ldw, k0; };
struct PackJobs { PackJob j[15]; };

__global__ void pack_all(PackJobs jobs) {
    const PackJob J = jobs.j[blockIdx.y];
    int idx = blockIdx.x * 256 + threadIdx.x;
    int total = J.Nout * J.K;
    if (idx >= total) return;
    int i = idx & 7;
    int l = (idx >> 3) & 63;
    int rest = idx >> 9;
    int NB = J.Nout >> 4;
    int nb = rest % NB;
    int ks = rest / NB;
    int k = ks * 32 + ((l >> 4) << 3) + i;
    int n = nb * 16 + (l & 15);
    J.P[idx] = (f16)J.W[(size_t)n * J.ldw + J.k0 + k];
}

// ---------------------------------------------------------------------------
// Generic C = A @ W^T + bias. AMODE: 0 = fp32 A (convert), 1 = f16 A.
// OMODE: 0 = f32 out, 1 = f16 out.
// ---------------------------------------------------------------------------
template <int AMODE, int OMODE>
__global__ void gemm_bias(const void* __restrict__ A_, const f16* __restrict__ P,
                          const float* __restrict__ bias, void* __restrict__ C_,
                          int M, int Nout, int K) {
    const int lane = threadIdx.x & 63, wave = threadIdx.x >> 6;
    const int wm = wave >> 1, wn = wave & 1;
    const int rb = blockIdx.x * 64 + wm * 32;
    const int cb = blockIdx.y * 64 + wn * 32;
    const int NB = Nout >> 4;
    const int kl = (lane >> 4) << 3;
    int r0 = rb + (lane & 15);
    int r1 = r0 + 16;
    int rc0 = r0 < M ? r0 : M - 1;
    int rc1 = r1 < M ? r1 : M - 1;
    f32x4 acc[2][2] = {};
    for (int ks = 0; ks < (K >> 5); ++ks) {
        int kb = ks * 32 + kl;
        f16x8 a0, a1;
        if constexpr (AMODE == 1) {
            const f16* A = (const f16*)A_;
            a0 = *(const f16x8*)(A + (size_t)rc0 * K + kb);
            a1 = *(const f16x8*)(A + (size_t)rc1 * K + kb);
        } else {
            const float* A = (const float*)A_;
            const float* p0 = A + (size_t)rc0 * K + kb;
            const float* p1 = A + (size_t)rc1 * K + kb;
#pragma unroll
            for (int i = 0; i < 8; ++i) { a0[i] = (f16)p0[i]; a1[i] = (f16)p1[i]; }
        }
#pragma unroll
        for (int nf = 0; nf < 2; ++nf) {
            int nb = (cb >> 4) + nf;
            f16x8 b = *(const f16x8*)(P + (((size_t)ks * NB + nb) * 64 + lane) * 8);
            acc[0][nf] = __builtin_amdgcn_mfma_f32_16x16x32_f16(a0, b, acc[0][nf], 0, 0, 0);
            acc[1][nf] = __builtin_amdgcn_mfma_f32_16x16x32_f16(a1, b, acc[1][nf], 0, 0, 0);
        }
    }
#pragma unroll
    for (int mf = 0; mf < 2; ++mf)
#pragma unroll
        for (int nf = 0; nf < 2; ++nf)
#pragma unroll
            for (int reg = 0; reg < 4; ++reg) {
                int row = rb + mf * 16 + ((lane >> 4) << 2) + reg;
                int col = cb + nf * 16 + (lane & 15);
                if (row < M) {
                    float v = acc[mf][nf][reg] + bias[col];
                    if constexpr (OMODE == 0)
                        ((float*)C_)[(size_t)row * Nout + col] = v;
                    else
                        ((f16*)C_)[(size_t)row * Nout + col] = (f16)v;
                }
            }
}

// ---------------------------------------------------------------------------
// Per-node message GEMMs: Gs = unf16 @ Ws^T + bih (+ bhh for r,z gates),
// Gd = unf16 @ Wd^T; gate-interleaved G[node*1024 + (col&255)*4 + (col>>8)].
// Folding bhh_r/bhh_z here (once per NODE) removes them from the edge
// epilogue (once per EDGE) — bhh_n cannot fold (it multiplies through r).
// grid (157, 24): by<12 -> Gs, by>=12 -> Gd.
// ---------------------------------------------------------------------------
__global__ void gemm_gi2(const f16* __restrict__ A,
                         const f16* __restrict__ Ps, const f16* __restrict__ Pd,
                         const float* __restrict__ bias, const float* __restrict__ bhh,
                         f16* __restrict__ Gs, f16* __restrict__ Gd, int M) {
    const int by = blockIdx.y;
    const bool isD = by >= 12;
    const f16* P = isD ? Pd : Ps;
    f16* G = isD ? Gd : Gs;
    const int byy = isD ? by - 12 : by;
    const int lane = threadIdx.x & 63, wave = threadIdx.x >> 6;
    const int wm = wave >> 1, wn = wave & 1;
    const int rb = blockIdx.x * 64 + wm * 32;
    const int cb = byy * 64 + wn * 32;
    const int NB = 48;
    const int kl = (lane >> 4) << 3;
    int r0 = rb + (lane & 15);
    int r1 = r0 + 16;
    int rc0 = r0 < M ? r0 : M - 1;
    int rc1 = r1 < M ? r1 : M - 1;
    f32x4 acc[2][2] = {};
    for (int ks = 0; ks < 8; ++ks) {
        int kb = ks * 32 + kl;
        f16x8 a0 = *(const f16x8*)(A + (size_t)rc0 * 256 + kb);
        f16x8 a1 = *(const f16x8*)(A + (size_t)rc1 * 256 + kb);
#pragma unroll
        for (int nf = 0; nf < 2; ++nf) {
            int nb = (cb >> 4) + nf;
            f16x8 b = *(const f16x8*)(P + (((size_t)ks * NB + nb) * 64 + lane) * 8);
            acc[0][nf] = __builtin_amdgcn_mfma_f32_16x16x32_f16(a0, b, acc[0][nf], 0, 0, 0);
            acc[1][nf] = __builtin_amdgcn_mfma_f32_16x16x32_f16(a1, b, acc[1][nf], 0, 0, 0);
        }
    }
#pragma unroll
    for (int mf = 0; mf < 2; ++mf)
#pragma unroll
        for (int nf = 0; nf < 2; ++nf)
#pragma unroll
            for (int reg = 0; reg < 4; ++reg) {
                int row = rb + mf * 16 + ((lane >> 4) << 2) + reg;
                int col = cb + nf * 16 + (lane & 15);
                if (row < M) {
                    float v = acc[mf][nf][reg];
                    if (!isD) {
                        v += bias[col];
                        if (col < 512) v += bhh[col];   // fold bhh_r, bhh_z
                    }
                    G[(size_t)row * 1024 + (col & 255) * 4 + (col >> 8)] = (f16)v;
                }
            }
}

// fast activations; tail-safe without clamps (inf handled by rcp -> 0)
__device__ inline float sigmoidf_(float x) {
    return __fdividef(1.f, 1.f + __expf(-x));
}
__device__ inline float tanhf_(float x) {
    float t = __expf(2.f * x);
    return 1.f - __fdividef(2.f, t + 1.f);
}

// ---------------------------------------------------------------------------
// Fused edge GRU + segment-sum: 32-edge tiles, 512 thr = 8 waves, grid 10000.
// Wave tile = 32 edges x 32 cols (acc[3][2][2] = 48 regs, ~112 total ->
// 4 waves/SIMD, ~2 independent blocks/CU). Transposed MFMA
// (gh^T = Whh @ uef^T), in-place on uef, fused run-wise atomic segment-sum.
// bhh_r/bhh_z pre-folded into Gs; only bhh_n loaded here.
// ---------------------------------------------------------------------------
__global__ __launch_bounds__(512, 4) void edge_gru(
        const f16* __restrict__ Gs, const f16* __restrict__ Gd,
        f16* __restrict__ uef,
        const int* __restrict__ src, const int* __restrict__ dst,
        const int* __restrict__ eidx,
        const f16* __restrict__ Phh, const float* __restrict__ bhh,
        float* __restrict__ agg) {
    __shared__ int s_eid[32];
    __shared__ int s_src[32];
    __shared__ int s_dst[32];
    __shared__ char lds_h[32 * 528];
    const int t = threadIdx.x;
    const int p0 = blockIdx.x * 32;
    if (t < 32) {
        int e = eidx[p0 + t];
        s_eid[t] = e;
        s_src[t] = src[e];
        s_dst[t] = dst[e];
    }
#pragma unroll
    for (int i = 0; i < 2; ++i) {
        int s = t + i * 512;
        int row = s >> 5, seg = s & 31;
        int e = eidx[p0 + row];
        f16x8 v = *(const f16x8*)(uef + (size_t)e * 256 + seg * 8);
        *(f16x8*)(lds_h + row * 528 + seg * 16) = v;
    }
    __syncthreads();
    const int lane = t & 63;
    const int wv = t >> 6;
    const int klb = (lane >> 4) << 4;
    const int erow = lane & 15;
    f32x4 acc[3][2][2] = {};
#pragma unroll
    for (int ks = 0; ks < 8; ++ks) {
        f16x8 b[2];
#pragma unroll
        for (int eg = 0; eg < 2; ++eg)
            b[eg] = *(const f16x8*)(lds_h + (eg * 16 + erow) * 528 + ks * 64 + klb);
#pragma unroll
        for (int g = 0; g < 3; ++g) {
#pragma unroll
            for (int jg = 0; jg < 2; ++jg) {
                f16x8 a = *(const f16x8*)(Phh + (size_t)g * 65536
                                          + (((size_t)ks * 16 + wv * 2 + jg) * 64 + lane) * 8);
#pragma unroll
                for (int eg = 0; eg < 2; ++eg)
                    acc[g][jg][eg] = __builtin_amdgcn_mfma_f32_16x16x32_f16(a, b[eg], acc[g][jg][eg], 0, 0, 0);
            }
        }
    }
    __syncthreads();
#pragma unroll
    for (int jg = 0; jg < 2; ++jg) {
        const int j0 = (wv * 2 + jg) * 16 + ((lane >> 4) << 2);
        const f32x4 bhn = *(const f32x4*)(bhh + 512 + j0);
#pragma unroll
        for (int eg = 0; eg < 2; ++eg) {
            const int rr = eg * 16 + erow;
            const int sn = s_src[rr], dn = s_dst[rr];
            f16x16 gsv = *(const f16x16*)(Gs + (size_t)sn * 1024 + j0 * 4);
            f16x16 gdv = *(const f16x16*)(Gd + (size_t)dn * 1024 + j0 * 4);
            f16x4 hv = *(const f16x4*)(lds_h + rr * 528 + j0 * 2);
            f16x4 outv;
#pragma unroll
            for (int q = 0; q < 4; ++q) {
                float ir = (float)gsv[q * 4 + 0] + (float)gdv[q * 4 + 0];
                float iz = (float)gsv[q * 4 + 1] + (float)gdv[q * 4 + 1];
                float in = (float)gsv[q * 4 + 2] + (float)gdv[q * 4 + 2];
                float r = sigmoidf_(ir + acc[0][jg][eg][q]);
                float z = sigmoidf_(iz + acc[1][jg][eg][q]);
                float nn = tanhf_(in + r * (acc[2][jg][eg][q] + bhn[q]));
                float h = (float)hv[q];
                outv[q] = (f16)(nn + z * (h - nn));
            }
            *(f16x4*)(lds_h + rr * 528 + j0 * 2) = outv;
        }
    }
    __syncthreads();
#pragma unroll
    for (int i = 0; i < 2; ++i) {
        int s = t + i * 512;
        int row = s >> 5, seg = s & 31;
        f16x8 v = *(const f16x8*)(lds_h + row * 528 + seg * 16);
        *(f16x8*)(uef + (size_t)s_eid[row] * 256 + seg * 8) = v;
    }
    {
        const int c = t & 255;
        const int q = t >> 8;
        float a = 0.f;
        int d = s_dst[q * 16];
#pragma unroll
        for (int r = q * 16; r < q * 16 + 16; ++r) {
            a += (float)*(const f16*)(lds_h + r * 528 + c * 2);
            int dn = (r < 31) ? s_dst[r + 1] : -1;
            if (r == q * 16 + 15 || dn != d) {
                atomicAdd(&agg[(size_t)d * 256 + c], a);
                a = 0.f;
                d = dn;
            }
        }
    }
}

// ---------------------------------------------------------------------------
// Fused node GRU, IN-PLACE on unf16 (f16 state). Block: 64 nodes x 256 cols.
// ---------------------------------------------------------------------------
__global__ __launch_bounds__(1024) void node_gru(
        const float* __restrict__ agg, f16* __restrict__ unf16,
        const f16* __restrict__ Pih, const f16* __restrict__ Phh,
        const float* __restrict__ bih, const float* __restrict__ bhh, int M) {
    const int lane = threadIdx.x & 63, wave = threadIdx.x >> 6;
    const int wm = wave & 1, wn = wave >> 1;
    const int rb = blockIdx.x * 64 + wm * 32;
    const int cb = wn * 32;
    const int nb0 = wn * 2;
    const int kl = (lane >> 4) << 3;
    int r0 = rb + (lane & 15), r1 = r0 + 16;
    int rc0 = r0 < M ? r0 : M - 1;
    int rc1 = r1 < M ? r1 : M - 1;
    f32x4 acc[4][2][2] = {};
#pragma unroll
    for (int ks = 0; ks < 8; ++ks) {
        const float* p0 = agg + (size_t)rc0 * 256 + ks * 32 + kl;
        const float* p1 = agg + (size_t)rc1 * 256 + ks * 32 + kl;
        f16x8 a0, a1;
#pragma unroll
        for (int i = 0; i < 8; ++i) { a0[i] = (f16)p0[i]; a1[i] = (f16)p1[i]; }
#pragma unroll
        for (int g = 0; g < 3; ++g) {
            const f16* Pg = Pih + (size_t)g * (256 * 256);
#pragma unroll
            for (int nf = 0; nf < 2; ++nf) {
                f16x8 b = *(const f16x8*)(Pg + (((size_t)ks * 16 + nb0 + nf) * 64 + lane) * 8);
                acc[g][0][nf] = __builtin_amdgcn_mfma_f32_16x16x32_f16(a0, b, acc[g][0][nf], 0, 0, 0);
                acc[g][1][nf] = __builtin_amdgcn_mfma_f32_16x16x32_f16(a1, b, acc[g][1][nf], 0, 0, 0);
            }
        }
    }
#pragma unroll
    for (int ks = 0; ks < 8; ++ks) {
        f16x8 a0 = *(const f16x8*)(unf16 + (size_t)rc0 * 256 + ks * 32 + kl);
        f16x8 a1 = *(const f16x8*)(unf16 + (size_t)rc1 * 256 + ks * 32 + kl);
#pragma unroll
        for (int g = 0; g < 3; ++g) {
            const f16* Pg = Phh + (size_t)g * (256 * 256);
            const int tgt = (g == 2) ? 3 : g;
#pragma unroll
            for (int nf = 0; nf < 2; ++nf) {
                f16x8 b = *(const f16x8*)(Pg + (((size_t)ks * 16 + nb0 + nf) * 64 + lane) * 8);
                acc[tgt][0][nf] = __builtin_amdgcn_mfma_f32_16x16x32_f16(a0, b, acc[tgt][0][nf], 0, 0, 0);
                acc[tgt][1][nf] = __builtin_amdgcn_mfma_f32_16x16x32_f16(a1, b, acc[tgt][1][nf], 0, 0, 0);
            }
        }
    }
    __syncthreads();
#pragma unroll
    for (int mf = 0; mf < 2; ++mf) {
        const int row = rb + mf * 16 + ((lane >> 4) << 2);
#pragma unroll
        for (int nf = 0; nf < 2; ++nf) {
            const int j = cb + nf * 16 + (lane & 15);
            const float b_r = bih[j] + bhh[j];
            const float b_z = bih[256 + j] + bhh[256 + j];
            const float b_i = bih[512 + j];
            const float b_h = bhh[512 + j];
#pragma unroll
            for (int reg = 0; reg < 4; ++reg) {
                const int rr = row + reg;
                if (rr < M) {
                    float r = sigmoidf_(acc[0][mf][nf][reg] + b_r);
                    float z = sigmoidf_(acc[1][mf][nf][reg] + b_z);
                    float nn = tanhf_(acc[2][mf][nf][reg] + b_i + r * (acc[3][mf][nf][reg] + b_h));
                    float h = (float)unf16[(size_t)rr * 256 + j];
                    unf16[(size_t)rr * 256 + j] = (f16)(nn + z * (h - nn));
                }
            }
        }
    }
}

// ---------------------------------------------------------------------------
// CSR build (dst-sorted edge order)
// ---------------------------------------------------------------------------
__global__ void hist_k(const int* __restrict__ dst, int* __restrict__ cnt, int E) {
    int e = blockIdx.x * 256 + threadIdx.x;
    if (e < E) atomicAdd(&cnt[dst[e]], 1);
}

__global__ void scan_k(const int* __restrict__ cnt, int* __restrict__ rowptr, int n) {
    __shared__ int s[1024];
    __shared__ int carry_s;
    if (threadIdx.x == 0) { carry_s = 0; rowptr[0] = 0; }
    __syncthreads();
    for (int base = 0; base < n; base += 1024) {
        int i = base + (int)threadIdx.x;
        int v = (i < n) ? cnt[i] : 0;
        s[threadIdx.x] = v;
        __syncthreads();
        for (int off = 1; off < 1024; off <<= 1) {
            int tv = (threadIdx.x >= (unsigned)off) ? s[threadIdx.x - off] : 0;
            __syncthreads();
            s[threadIdx.x] += tv;
            __syncthreads();
        }
        if (i < n) rowptr[i + 1] = carry_s + s[threadIdx.x];
        __syncthreads();
        if (threadIdx.x == 0) carry_s += s[1023];
        __syncthreads();
    }
}

__global__ void scatter_k(const int* __restrict__ dst, const int* __restrict__ rowptr,
                          int* __restrict__ cnt2, int* __restrict__ eidx, int E) {
    int e = blockIdx.x * 256 + threadIdx.x;
    if (e < E) {
        int d = dst[e];
        int p = rowptr[d] + atomicAdd(&cnt2[d], 1);
        eidx[p] = e;
    }
}

// ---------------------------------------------------------------------------
extern "C" void kernel_launch(void* const* d_in, const int* in_sizes, int n_in,
                              void* d_out, int out_size, void* d_ws, size_t ws_size,
                              hipStream_t stream) {
    (void)in_sizes; (void)n_in; (void)out_size; (void)ws_size;
    const float* nf    = (const float*)d_in[0];
    const float* ef    = (const float*)d_in[1];
    const int*   src   = (const int*)d_in[2];
    const int*   dst   = (const int*)d_in[3];
    const float* Wne   = (const float*)d_in[4];
    const float* bne   = (const float*)d_in[5];
    const float* Wee   = (const float*)d_in[6];
    const float* bee   = (const float*)d_in[7];
    const float* Wih_e = (const float*)d_in[8];
    const float* Whh_e = (const float*)d_in[9];
    const float* bih_e = (const float*)d_in[10];
    const float* bhh_e = (const float*)d_in[11];
    const float* Wih_n = (const float*)d_in[12];
    const float* Whh_n = (const float*)d_in[13];
    const float* bih_n = (const float*)d_in[14];
    const float* bhh_n = (const float*)d_in[15];
    const float* Wnd   = (const float*)d_in[16];
    const float* bnd   = (const float*)d_in[17];
    const float* Wed   = (const float*)d_in[18];
    const float* bed   = (const float*)d_in[19];

    char* ws = (char*)d_ws;
    size_t off = 0;
    auto alloc = [&](size_t bytes) -> void* {
        void* p = ws + off;
        off += (bytes + 255) & ~(size_t)255;
        return p;
    };
    f16*   uefA  = (f16*)alloc((size_t)NEDGES * 256 * 2);
    f16*   unf16 = (f16*)alloc((size_t)NNODES * 256 * 2);
    float* agg   = (float*)alloc((size_t)NNODES * 256 * 4);
    f16*   Gs    = (f16*)alloc((size_t)NNODES * 1024 * 2);
    f16*   Gd    = (f16*)alloc((size_t)NNODES * 1024 * 2);
    f16*   Ps_e  = (f16*)alloc((size_t)768 * 256 * 2);
    f16*   Pd_e  = (f16*)alloc((size_t)768 * 256 * 2);
    f16*   Phh_e = (f16*)alloc((size_t)3 * 256 * 256 * 2);
    f16*   Pih_n = (f16*)alloc((size_t)3 * 256 * 256 * 2);
    f16*   Phh_n = (f16*)alloc((size_t)3 * 256 * 256 * 2);
    f16*   Pne   = (f16*)alloc((size_t)256 * 128 * 2);
    f16*   Pee   = (f16*)alloc((size_t)256 * 64 * 2);
    f16*   Pnd   = (f16*)alloc((size_t)128 * 256 * 2);
    f16*   Ped   = (f16*)alloc((size_t)64 * 256 * 2);
    int* cnt    = (int*)alloc((size_t)NNODES * 4);
    int* cnt2   = (int*)alloc((size_t)NNODES * 4);
    int* rowptr = (int*)alloc((size_t)(NNODES + 1) * 4);
    int* eidx   = (int*)alloc((size_t)NEDGES * 4);

    hipMemsetAsync(cnt, 0, (size_t)NNODES * 4, stream);
    hipMemsetAsync(cnt2, 0, (size_t)NNODES * 4, stream);

    // pack all weights in one launch
    PackJobs jobs;
    jobs.j[0]  = {Wih_e, Ps_e, 768, 256, 512, 0};
    jobs.j[1]  = {Wih_e, Pd_e, 768, 256, 512, 256};
    for (int g = 0; g < 3; ++g) {
        jobs.j[2 + g] = {Whh_e + (size_t)g * 65536, Phh_e + (size_t)g * 65536, 256, 256, 256, 0};
        jobs.j[5 + g] = {Wih_n + (size_t)g * 65536, Pih_n + (size_t)g * 65536, 256, 256, 256, 0};
        jobs.j[8 + g] = {Whh_n + (size_t)g * 65536, Phh_n + (size_t)g * 65536, 256, 256, 256, 0};
    }
    jobs.j[11] = {Wne, Pne, 256, 128, 128, 0};
    jobs.j[12] = {Wee, Pee, 256, 64, 64, 0};
    jobs.j[13] = {Wnd, Pnd, 128, 256, 256, 0};
    jobs.j[14] = {Wed, Ped, 64, 256, 256, 0};
    pack_all<<<dim3(768, 15), 256, 0, stream>>>(jobs);

    // CSR by dst (gives dst-sorted eidx)
    hist_k<<<(NEDGES + 255) / 256, 256, 0, stream>>>(dst, cnt, NEDGES);
    scan_k<<<1, 1024, 0, stream>>>(cnt, rowptr, NNODES);
    scatter_k<<<(NEDGES + 255) / 256, 256, 0, stream>>>(dst, rowptr, cnt2, eidx, NEDGES);

    // encode
    gemm_bias<0, 1><<<dim3(157, 4), 256, 0, stream>>>(nf, Pne, bne, unf16, NNODES, 256, 128);
    gemm_bias<0, 1><<<dim3(5000, 4), 256, 0, stream>>>(ef, Pee, bee, uefA, NEDGES, 256, 64);

    // message passing
    for (int it = 0; it < 3; ++it) {
        gemm_gi2<<<dim3(157, 24), 256, 0, stream>>>(unf16, Ps_e, Pd_e, bih_e, bhh_e, Gs, Gd, NNODES);
        hipMemsetAsync(agg, 0, (size_t)NNODES * 256 * 4, stream);
        edge_gru<<<10000, 512, 0, stream>>>(Gs, Gd, uefA, src, dst, eidx, Phh_e, bhh_e, agg);
        node_gru<<<157, 1024, 0, stream>>>(agg, unf16, Pih_n, Phh_n, bih_n, bhh_n, NNODES);
    }

    // decode
    gemm_bias<1, 0><<<dim3(157, 2), 256, 0, stream>>>(unf16, Pnd, bnd, d_out, NNODES, 128, 256);
    gemm_bias<1, 0><<<dim3(5000, 1), 256, 0, stream>>>(uefA, Ped, bed,
                                                       (float*)d_out + (size_t)NNODES * 128,
                                                       NEDGES, 64, 256);
}